// Round 23
// baseline (436.178 us; speedup 1.0000x reference)
//
#include <hip/hip_runtime.h>
#include <hip/hip_bf16.h>

// ---------------------------------------------------------------------------
// QueryGuidedFusionNet forward on MI355X.
// Round 23: deepen k_gemm_n64 pipeline 5->10 buffers (LDS 60->120KB, still
// 1 block/CU). r18 counters: FFN2-N64 at 1.1TB/s, 78% vmcnt-stall = latency x
// outstanding-bytes bound (12KB/wave in flight ~ 13B/cy/CU vs 24.6 share).
// Doubling in-flight should ~double the fill rate. Rest = r22 (428us).
// ---------------------------------------------------------------------------

typedef __attribute__((ext_vector_type(8))) short short8;   // 8 bf16
typedef __attribute__((ext_vector_type(4))) float f32x4;

#define DEV static __device__ __forceinline__

DEV unsigned short f2bf(float f) {
    unsigned u = __float_as_uint(f);
    u += 0x7fffu + ((u >> 16) & 1u);          // RNE
    return (unsigned short)(u >> 16);
}
DEV float bf2f(unsigned short u) {
    return __uint_as_float(((unsigned)u) << 16);
}

// ------------------------- multi-tensor convert (balanced) ------------------
struct CvtPack {
    const float* src[9];
    unsigned short* dst[9];
    long start16[10];       // prefix sums in 16-element units
};

__global__ __launch_bounds__(256)
void k_cvt_multi(CvtPack p, long total16) {
    long i = (long)blockIdx.x * blockDim.x + threadIdx.x;
    long stride = (long)gridDim.x * blockDim.x;
    for (; i < total16; i += stride) {
        int t = 0;
#pragma unroll
        for (int k = 1; k < 9; ++k) t += (i >= p.start16[k]) ? 1 : 0;
        long off = i - p.start16[t];
        const f32x4* s = (const f32x4*)p.src[t] + off * 4;
        f32x4 a = s[0];
        f32x4 b = s[1];
        f32x4 c = s[2];
        f32x4 d = s[3];
        short8 o0, o1;
        o0[0] = (short)f2bf(a[0]); o0[1] = (short)f2bf(a[1]);
        o0[2] = (short)f2bf(a[2]); o0[3] = (short)f2bf(a[3]);
        o0[4] = (short)f2bf(b[0]); o0[5] = (short)f2bf(b[1]);
        o0[6] = (short)f2bf(b[2]); o0[7] = (short)f2bf(b[3]);
        o1[0] = (short)f2bf(c[0]); o1[1] = (short)f2bf(c[1]);
        o1[2] = (short)f2bf(c[2]); o1[3] = (short)f2bf(c[3]);
        o1[4] = (short)f2bf(d[0]); o1[5] = (short)f2bf(d[1]);
        o1[6] = (short)f2bf(d[2]); o1[7] = (short)f2bf(d[3]);
        short8* dp = (short8*)p.dst[t] + off * 2;
        dp[0] = o0;
        dp[1] = o1;
    }
}

// ---- fused QK^T + mask + softmax -> compact bf16 P --------------------------
// One block per (b,h): 16 waves compute the full 128 x Lpad score tile.
// NJ = cols-per-wave/16 (8 for Lpad=512, 4 for Lpad=256). K = 64 exact.
template<int NJ>
__global__ __launch_bounds__(1024)
void k_qks(const unsigned short* __restrict__ Q, const unsigned short* __restrict__ Km,
           unsigned short* __restrict__ P, const int* __restrict__ mask,
           int L, int lda, int ldb, int H, long sQb, long sKb, float scale)
{
    const int Lpad = NJ * 64;
    __shared__ unsigned short sm[8192 + 32768];   // Q 16KB + K <=64KB
    __shared__ float redm[128][4];
    __shared__ float reds[128][4];

    int z = blockIdx.z;
    int b = z / H, h = z - b * H;
    const unsigned short* Qp = Q + (long)b * sQb + (long)h * 64;
    const unsigned short* Kp = Km + (long)b * sKb + (long)h * 64;
    unsigned short* Pp = P + (long)z * 128 * Lpad;
    const int* mrow = mask + (long)b * L;

    int t = threadIdx.x;
    int wid = t >> 6, lane = t & 63;
    int lrow = lane & 15, kgrp = lane >> 4;
    int wm = (wid >> 2) * 32;                 // m-wave: 4 x 32 rows
    int wn = (wid & 3) * (NJ * 16);           // n-wave: 4 x NJ*16 cols

    // ---- stage Q (16KB, 1 round) + K (NJ/2 rounds of 16KB) ----
    {
        int d = t * 16;
        int row = d >> 7;
        int colb = (d & 127) ^ ((row & 7) << 4);
        __builtin_amdgcn_global_load_lds(
            (const __attribute__((address_space(1))) unsigned int*)(Qp + (long)row * lda + (colb >> 1)),
            (__attribute__((address_space(3))) unsigned int*)(sm + (d >> 1)), 16, 0, 0);
    }
#pragma unroll
    for (int r = 0; r < NJ / 2; ++r) {
        int full = r * 16384 + t * 16;
        int row = full >> 7;
        int colb = (full & 127) ^ ((row & 7) << 4);
        int kr = row; if (kr > L - 1) kr = L - 1;
        __builtin_amdgcn_global_load_lds(
            (const __attribute__((address_space(1))) unsigned int*)(Kp + (long)kr * ldb + (colb >> 1)),
            (__attribute__((address_space(3))) unsigned int*)(sm + 8192 + (full >> 1)), 16, 0, 0);
    }
    asm volatile("s_waitcnt vmcnt(0)" ::: "memory");
    __builtin_amdgcn_sched_barrier(0);
    __syncthreads();

    // ---- QK^T: acc[2][NJ], K=64 (2 k-chunks) ----
    const char* Qs = (const char*)sm;
    const char* Ks = (const char*)(sm + 8192);
    f32x4 acc[2][NJ] = {};
#pragma unroll
    for (int ks = 0; ks < 2; ++ks) {
        int kb = ks * 64 + kgrp * 16;
        short8 a[2], bb[NJ];
#pragma unroll
        for (int i = 0; i < 2; ++i) {
            int row = wm + i * 16 + lrow;
            a[i] = *(const short8*)(Qs + row * 128 + (kb ^ ((row & 7) << 4)));
        }
#pragma unroll
        for (int j = 0; j < NJ; ++j) {
            int row = wn + j * 16 + lrow;
            bb[j] = *(const short8*)(Ks + row * 128 + (kb ^ ((row & 7) << 4)));
        }
#pragma unroll
        for (int i = 0; i < 2; ++i)
#pragma unroll
            for (int j = 0; j < NJ; ++j)
                acc[i][j] = __builtin_amdgcn_mfma_f32_16x16x32_bf16(a[i], bb[j], acc[i][j], 0, 0, 0);
    }

    // ---- column validity (same for all rows of this thread) ----
    bool okj[NJ];
#pragma unroll
    for (int j = 0; j < NJ; ++j) {
        int c = wn + j * 16 + lrow;
        okj[j] = (c < L) && (mrow[c] != 0);
    }

    // ---- pass 1: row max (16-lane shfl reduce + cross-wave LDS) ----
    int nw = wid & 3;
#pragma unroll
    for (int i = 0; i < 2; ++i) {
#pragma unroll
        for (int e = 0; e < 4; ++e) {
            float m = -INFINITY;
#pragma unroll
            for (int j = 0; j < NJ; ++j)
                if (okj[j]) m = fmaxf(m, acc[i][j][e] * scale);
#pragma unroll
            for (int d = 1; d < 16; d <<= 1) m = fmaxf(m, __shfl_xor(m, d, 64));
            int rl = wm + i * 16 + kgrp * 4 + e;
            if (lrow == 0) redm[rl][nw] = m;
        }
    }
    __syncthreads();

    // ---- pass 2: exp + row sum ----
#pragma unroll
    for (int i = 0; i < 2; ++i) {
#pragma unroll
        for (int e = 0; e < 4; ++e) {
            int rl = wm + i * 16 + kgrp * 4 + e;
            float m = fmaxf(fmaxf(redm[rl][0], redm[rl][1]),
                            fmaxf(redm[rl][2], redm[rl][3]));
            float s = 0.f;
#pragma unroll
            for (int j = 0; j < NJ; ++j) {
                float ev = okj[j] ? __expf(acc[i][j][e] * scale - m) : 0.0f;
                acc[i][j][e] = ev;
                s += ev;
            }
#pragma unroll
            for (int d = 1; d < 16; d <<= 1) s += __shfl_xor(s, d, 64);
            if (lrow == 0) reds[rl][nw] = s;
        }
    }
    __syncthreads();

    // ---- normalize + write compact bf16 P ----
#pragma unroll
    for (int i = 0; i < 2; ++i) {
#pragma unroll
        for (int e = 0; e < 4; ++e) {
            int rl = wm + i * 16 + kgrp * 4 + e;
            float inv = 1.0f / (reds[rl][0] + reds[rl][1] + reds[rl][2] + reds[rl][3]);
            unsigned short* pr = Pp + (long)rl * Lpad;
#pragma unroll
            for (int j = 0; j < NJ; ++j) {
                int c = wn + j * 16 + lrow;
                pr[c] = f2bf(acc[i][j][e] * inv);
            }
        }
    }
}

// --------------------- GEMM NT 256x256 (16 waves, BK=64) --------------------
__global__ __launch_bounds__(1024)
void k_gemm_nt256(const unsigned short* __restrict__ A, const unsigned short* __restrict__ B,
                  const float* __restrict__ bias,
                  float* __restrict__ outF, unsigned short* __restrict__ outB,
                  int M, int N, int K, int lda, int ldb, int ldc,
                  long sPart,
                  unsigned short* __restrict__ vT, int vColOff, long sVz, int vLd)
{
    __shared__ unsigned short smem[2 * 32768];   // 2 bufs x (A32KB + B32KB)

    unsigned gx = gridDim.x, gy = gridDim.y;
    unsigned nwg = gx * gy * gridDim.z;
    unsigned lin = (blockIdx.z * gy + blockIdx.y) * gx + blockIdx.x;
    unsigned bx = blockIdx.x, by = blockIdx.y, bz = blockIdx.z;
    if ((nwg & 7u) == 0u) {
        unsigned cpx = nwg >> 3;
        unsigned s = (lin & 7u) * cpx + (lin >> 3);
        bx = s % gx; unsigned r2 = s / gx;
        by = r2 % gy; bz = r2 / gy;
    }
    int s_k = (int)bz;
    const unsigned short* Ap = A + (long)s_k * K;
    const unsigned short* Bp = B + (long)s_k * K;
    float* outFp = outF ? outF + (long)s_k * sPart : nullptr;
    unsigned short* outBp = outB ? outB + (long)s_k * sPart : nullptr;

    int t = threadIdx.x;
    int wid = t >> 6, lane = t & 63;
    int lrow = lane & 15, kgrp = lane >> 4;
    int tm = by * 256, tn = bx * 256;
    int wm = (wid >> 2) * 64, wn = (wid & 3) * 64;

    auto stage = [&](int buf, int k0) {
#pragma unroll
        for (int r = 0; r < 2; ++r) {
            int d = r * 16384 + t * 16;                 // byte in 32KB tile
            int row = d >> 7;                           // 128B rows
            int colb = (d & 127) ^ ((row & 7) << 4);    // inverse swizzle
            int gr = tm + row; if (gr > M - 1) gr = M - 1;
            const unsigned short* srcA = Ap + (long)gr * lda + k0 + (colb >> 1);
            unsigned short* dstA = smem + ((buf * 65536 + d) >> 1);
            __builtin_amdgcn_global_load_lds(
                (const __attribute__((address_space(1))) unsigned int*)srcA,
                (__attribute__((address_space(3))) unsigned int*)dstA, 16, 0, 0);
            int gn = tn + row; if (gn > N - 1) gn = N - 1;
            const unsigned short* srcB = Bp + (long)gn * ldb + k0 + (colb >> 1);
            unsigned short* dstB = smem + ((buf * 65536 + 32768 + d) >> 1);
            __builtin_amdgcn_global_load_lds(
                (const __attribute__((address_space(1))) unsigned int*)srcB,
                (__attribute__((address_space(3))) unsigned int*)dstB, 16, 0, 0);
        }
    };

    f32x4 acc[4][4] = {};
    int nt = K >> 6;

    stage(0, 0);

    for (int ti = 0; ti < nt; ++ti) {
        int cur = ti & 1;
        if (ti + 1 < nt) {
            stage(cur ^ 1, (ti + 1) << 6);   // 4 new VMEM instrs in flight
            asm volatile("s_waitcnt vmcnt(4)" ::: "memory");   // current tile done
        } else {
            asm volatile("s_waitcnt vmcnt(0)" ::: "memory");
        }
        __builtin_amdgcn_sched_barrier(0);
        __builtin_amdgcn_s_barrier();
        __builtin_amdgcn_sched_barrier(0);

        const char* Ab = (const char*)smem + cur * 65536;
        const char* Bb = Ab + 32768;
#pragma unroll
        for (int ks = 0; ks < 2; ++ks) {
            short8 a[4], bb[4];
            int kb = ks * 64 + kgrp * 16;
#pragma unroll
            for (int i = 0; i < 4; ++i) {
                int row = wm + i * 16 + lrow;
                a[i] = *(const short8*)(Ab + row * 128 + (kb ^ ((row & 7) << 4)));
            }
#pragma unroll
            for (int j = 0; j < 4; ++j) {
                int row = wn + j * 16 + lrow;
                bb[j] = *(const short8*)(Bb + row * 128 + (kb ^ ((row & 7) << 4)));
            }
#pragma unroll
            for (int i = 0; i < 4; ++i)
#pragma unroll
                for (int j = 0; j < 4; ++j)
                    acc[i][j] = __builtin_amdgcn_mfma_f32_16x16x32_bf16(a[i], bb[j], acc[i][j], 0, 0, 0);
        }
        __builtin_amdgcn_s_barrier();   // protect buf before re-stage next iter
    }

#pragma unroll
    for (int i = 0; i < 4; ++i) {
        int rbase = tm + wm + i * 16 + kgrp * 4;
#pragma unroll
        for (int j = 0; j < 4; ++j) {
            int c = tn + wn + j * 16 + lrow;
            if (c >= N) continue;
            float bv = bias ? bias[c] : 0.0f;
            float v[4];
#pragma unroll
            for (int e = 0; e < 4; ++e) v[e] = acc[i][j][e] + bv;
            if (vT && c >= vColOff) {
                if (rbase + 3 < M) {
                    int hh = (c - vColOff) >> 6, dd = (c - vColOff) & 63;
                    int bb2 = rbase >> 9, l = rbase & 511;
                    ushort4 o = { f2bf(v[0]), f2bf(v[1]), f2bf(v[2]), f2bf(v[3]) };
                    *(ushort4*)(vT + (long)(bb2 * 16 + hh) * sVz + (long)dd * vLd + l) = o;
                }
            } else {
#pragma unroll
                for (int e = 0; e < 4; ++e) {
                    int r = rbase + e;
                    if (r >= M) continue;
                    long oidx = (long)r * ldc + c;
                    if (outFp) outFp[oidx] = v[e];
                    if (outBp) outBp[oidx] = f2bf(v[e]);
                }
            }
        }
    }
}

// --------------------- GEMM N64: 128x64 tile (4 waves, 10-deep) -------------
__global__ __launch_bounds__(256)
void k_gemm_n64(const unsigned short* __restrict__ A, const unsigned short* __restrict__ B,
                const float* __restrict__ bias, const float* __restrict__ res,
                float* __restrict__ outF, unsigned short* __restrict__ outB,
                int K, int lda, int ldb, int ldc,
                int H, long sAb, long sAh, long sBz, long sCb, long sCh, int gelu,
                int S, long sPart)
{
    __shared__ unsigned short smem[10 * 6144];   // 10 x (A 8KB + B 4KB) = 120KB

    unsigned gx = gridDim.x, gy = gridDim.y;
    unsigned nwg = gx * gy * gridDim.z;
    unsigned lin = (blockIdx.z * gy + blockIdx.y) * gx + blockIdx.x;
    unsigned bx = blockIdx.x, by = blockIdx.y, bz = blockIdx.z;
    if ((nwg & 7u) == 0u) {
        unsigned cpx = nwg >> 3;
        unsigned s = (lin & 7u) * cpx + (lin >> 3);
        bx = s % gx; unsigned r2 = s / gx;
        by = r2 % gy; bz = r2 / gy;
    }

    int zz = (int)bz;
    int s_k = 0;
    if (S > 1) { s_k = zz % S; zz /= S; }
    int b = zz / H, h = zz - b * H;
    const unsigned short* Ap = A + (long)b * sAb + (long)h * sAh + (long)s_k * K;
    const unsigned short* Bp = B + (long)zz * sBz + (long)s_k * K;
    float* outFp = outF;
    unsigned short* outBp = outB;
    if (outBp && S > 1) outBp += (long)s_k * sPart;
    long offC = (long)b * sCb + (long)h * sCh;

    int t = threadIdx.x;
    int wid = t >> 6, lane = t & 63;
    int lrow = lane & 15, kgrp = lane >> 4;
    int tm = by * 128, tn = bx * 64;
    int wm = wid * 32;

    auto stage = [&](int buf, int k0) {
#pragma unroll
        for (int r = 0; r < 2; ++r) {               // A: 128 rows x 64B
            int d = r * 4096 + t * 16;
            int row = d >> 6;
            int colb = (d & 63) ^ (((row >> 1) & 3) << 4);
            const unsigned short* srcA = Ap + (long)(tm + row) * lda + k0 + (colb >> 1);
            unsigned short* dstA = smem + ((buf * 12288 + d) >> 1);
            __builtin_amdgcn_global_load_lds(
                (const __attribute__((address_space(1))) unsigned int*)srcA,
                (__attribute__((address_space(3))) unsigned int*)dstA, 16, 0, 0);
        }
        {                                            // B: 64 rows x 64B
            int d = t * 16;
            int row = d >> 6;
            int colb = (d & 63) ^ (((row >> 1) & 3) << 4);
            const unsigned short* srcB = Bp + (long)(tn + row) * ldb + k0 + (colb >> 1);
            unsigned short* dstB = smem + ((buf * 12288 + 8192 + d) >> 1);
            __builtin_amdgcn_global_load_lds(
                (const __attribute__((address_space(1))) unsigned int*)srcB,
                (__attribute__((address_space(3))) unsigned int*)dstB, 16, 0, 0);
        }
    };

    f32x4 acc[2][4] = {};
    int nt = K >> 5;

    for (int p = 0; p < 9 && p < nt; ++p) stage(p, p << 5);

    for (int ti = 0; ti < nt; ++ti) {
        int cur = ti % 10;
        int rem = nt - 1 - ti;
        // wait until the 3 loads of buffer `cur` (the oldest) are complete:
        // outstanding stages = min(rem,8)+1, each 3 loads -> allow 3*min(rem,8)
        if (rem >= 8)      asm volatile("s_waitcnt vmcnt(24)" ::: "memory");
        else if (rem == 7) asm volatile("s_waitcnt vmcnt(21)" ::: "memory");
        else if (rem == 6) asm volatile("s_waitcnt vmcnt(18)" ::: "memory");
        else if (rem == 5) asm volatile("s_waitcnt vmcnt(15)" ::: "memory");
        else if (rem == 4) asm volatile("s_waitcnt vmcnt(12)" ::: "memory");
        else if (rem == 3) asm volatile("s_waitcnt vmcnt(9)"  ::: "memory");
        else if (rem == 2) asm volatile("s_waitcnt vmcnt(6)"  ::: "memory");
        else if (rem == 1) asm volatile("s_waitcnt vmcnt(3)"  ::: "memory");
        else               asm volatile("s_waitcnt vmcnt(0)"  ::: "memory");
        __builtin_amdgcn_sched_barrier(0);
        __builtin_amdgcn_s_barrier();
        __builtin_amdgcn_sched_barrier(0);

        if (ti + 9 < nt) stage((ti + 9) % 10, (ti + 9) << 5);

        const char* Ab = (const char*)smem + cur * 12288;
        const char* Bb = Ab + 8192;
        short8 a[2], bb[4];
#pragma unroll
        for (int i = 0; i < 2; ++i) {
            int row = wm + i * 16 + lrow;
            a[i] = *(const short8*)(Ab + row * 64 + ((kgrp * 16) ^ (((row >> 1) & 3) << 4)));
        }
#pragma unroll
        for (int j = 0; j < 4; ++j) {
            int row = j * 16 + lrow;
            bb[j] = *(const short8*)(Bb + row * 64 + ((kgrp * 16) ^ (((row >> 1) & 3) << 4)));
        }
#pragma unroll
        for (int i = 0; i < 2; ++i)
#pragma unroll
            for (int j = 0; j < 4; ++j)
                acc[i][j] = __builtin_amdgcn_mfma_f32_16x16x32_bf16(a[i], bb[j], acc[i][j], 0, 0, 0);
    }

#pragma unroll
    for (int i = 0; i < 2; ++i) {
        int rbase = tm + wm + i * 16 + kgrp * 4;
#pragma unroll
        for (int j = 0; j < 4; ++j) {
            int c = tn + j * 16 + lrow;
            float bv = bias ? bias[c] : 0.0f;
#pragma unroll
            for (int e = 0; e < 4; ++e) {
                int r = rbase + e;
                long oidx = offC + (long)r * ldc + c;
                float v = acc[i][j][e] + bv;
                if (res) v += res[oidx];
                if (gelu) v = 0.5f * v * (1.0f + erff(v * 0.70710678118654752f));
                if (outFp) outFp[oidx] = v;
                if (outBp) outBp[oidx] = f2bf(v);
            }
        }
    }
}

// ------------------------------ GEMM NT (pipelined 128²) --------------------
template<bool GELU>
__global__ __launch_bounds__(256)
void k_gemm_nt(const unsigned short* __restrict__ A, const unsigned short* __restrict__ B,
               const float* __restrict__ bias, const float* __restrict__ res,
               float* __restrict__ outF, unsigned short* __restrict__ outB,
               int M, int N, int K, int lda, int ldb, int ldc,
               int H, long sAb, long sAh, long sBb, long sBh, long sCb, long sCh,
               float scale, int S, long sPart,
               unsigned short* __restrict__ vT, int vColOff, long sVz, int vLd, int rpb)
{
    __shared__ unsigned short smem[5 * 8192];

    unsigned gx = gridDim.x, gy = gridDim.y, gz = gridDim.z;
    unsigned nwg = gx * gy * gz;
    unsigned lin = (blockIdx.z * gy + blockIdx.y) * gx + blockIdx.x;
    unsigned bx = blockIdx.x, by = blockIdx.y, bz = blockIdx.z;
    if ((nwg & 7u) == 0u) {
        unsigned cpx = nwg >> 3;
        unsigned s = (lin & 7u) * cpx + (lin >> 3);
        bx = s % gx; unsigned r2 = s / gx;
        by = r2 % gy; bz = r2 / gy;
    }

    int zz = (int)bz;
    int s_k = 0;
    if (S > 1) { s_k = zz % S; zz /= S; }
    int b = zz / H, h = zz - b * H;
    const unsigned short* Ap = A + (long)b * sAb + (long)h * sAh + (long)s_k * K;
    const unsigned short* Bp = B + (long)b * sBb + (long)h * sBh + (long)s_k * K;
    float* outFp = outF;
    if (outFp && S > 1) outFp += (long)s_k * sPart;
    unsigned short* outBp = outB;
    if (outBp && S > 1) outBp += (long)s_k * sPart;
    long offC = (long)b * sCb + (long)h * sCh;

    int t    = threadIdx.x;
    int wid  = t >> 6;
    int lane = t & 63;
    int lrow = lane & 15;
    int kgrp = lane >> 4;

    int tm = by * 128;
    int tn = bx * 128;
    int wm = (wid >> 1) * 64;
    int wn = (wid & 1) * 64;

    auto stage = [&](int buf, int k0) {
#pragma unroll
        for (int r = 0; r < 2; ++r) {
            int d = r * 4096 + t * 16;
            int row = d >> 6;
            int colb = (d & 63) ^ (((row >> 1) & 3) << 4);
            int gr = tm + row; if (gr > M - 1) gr = M - 1;
            const unsigned short* srcA = Ap + (long)gr * lda + k0 + (colb >> 1);
            unsigned short* dstA = smem + ((buf * 16384 + r * 4096 + wid * 1024) >> 1);
            __builtin_amdgcn_global_load_lds(
                (const __attribute__((address_space(1))) unsigned int*)srcA,
                (__attribute__((address_space(3))) unsigned int*)dstA, 16, 0, 0);
            int gn = tn + row; if (gn > N - 1) gn = N - 1;
            const unsigned short* srcB = Bp + (long)gn * ldb + k0 + (colb >> 1);
            unsigned short* dstB = smem + ((buf * 16384 + 8192 + r * 4096 + wid * 1024) >> 1);
            __builtin_amdgcn_global_load_lds(
                (const __attribute__((address_space(1))) unsigned int*)srcB,
                (__attribute__((address_space(3))) unsigned int*)dstB, 16, 0, 0);
        }
    };

    f32x4 acc[4][4] = {};
    int nt = K >> 5;

    for (int p = 0; p < 4 && p < nt; ++p) stage(p, p << 5);

    for (int ti = 0; ti < nt; ++ti) {
        int cur = ti % 5;
        int rem = nt - 1 - ti;
        if (rem >= 3)      asm volatile("s_waitcnt vmcnt(12)" ::: "memory");
        else if (rem == 2) asm volatile("s_waitcnt vmcnt(8)"  ::: "memory");
        else if (rem == 1) asm volatile("s_waitcnt vmcnt(4)"  ::: "memory");
        else               asm volatile("s_waitcnt vmcnt(0)"  ::: "memory");
        __builtin_amdgcn_sched_barrier(0);
        __builtin_amdgcn_s_barrier();
        __builtin_amdgcn_sched_barrier(0);

        if (ti + 4 < nt) stage((ti + 4) % 5, (ti + 4) << 5);

        const char* Ab = (const char*)smem + cur * 16384;
        const char* Bb = Ab + 8192;
        short8 a[4], bb[4];
#pragma unroll
        for (int i = 0; i < 4; ++i) {
            int row = wm + i * 16 + lrow;
            a[i] = *(const short8*)(Ab + row * 64 + ((kgrp * 16) ^ (((row >> 1) & 3) << 4)));
        }
#pragma unroll
        for (int j = 0; j < 4; ++j) {
            int row = wn + j * 16 + lrow;
            bb[j] = *(const short8*)(Bb + row * 64 + ((kgrp * 16) ^ (((row >> 1) & 3) << 4)));
        }
#pragma unroll
        for (int i = 0; i < 4; ++i)
#pragma unroll
            for (int j = 0; j < 4; ++j)
                acc[i][j] = __builtin_amdgcn_mfma_f32_16x16x32_bf16(a[i], bb[j], acc[i][j], 0, 0, 0);
    }

#pragma unroll
    for (int i = 0; i < 4; ++i) {
        int rbase = tm + wm + i * 16 + kgrp * 4;
#pragma unroll
        for (int j = 0; j < 4; ++j) {
            int c = tn + wn + j * 16 + lrow;
            if (c >= N) continue;
            float bv = bias ? bias[c] : 0.0f;
            if (vT && c >= vColOff) {
                int hh = (c - vColOff) >> 6, dd = (c - vColOff) & 63;
#pragma unroll
                for (int e = 0; e < 4; ++e) {
                    int r = rbase + e;
                    if (r >= M) continue;
                    float v = acc[i][j][e] * scale + bv;
                    int bb2 = r / rpb, l = r - bb2 * rpb;
                    vT[(long)(bb2 * 16 + hh) * sVz + (long)dd * vLd + l] = f2bf(v);
                }
                continue;
            }
#pragma unroll
            for (int e = 0; e < 4; ++e) {
                int r = rbase + e;
                if (r >= M) continue;
                float v = acc[i][j][e] * scale + bv;
                long oidx = offC + (long)r * ldc + c;
                if (res) v += res[oidx];
                if (GELU) v = 0.5f * v * (1.0f + erff(v * 0.70710678118654752f));
                if (outFp) outFp[oidx] = v;
                if (outBp) outBp[oidx] = f2bf(v);
            }
        }
    }
}

// -------------------- split-K reduce (bf16 partials) -------------------------
__global__ __launch_bounds__(256)
void k_redux_b(const unsigned short* __restrict__ part, long sPart, int S,
               const float* __restrict__ bias, const float* __restrict__ res,
               float* __restrict__ outF, unsigned short* __restrict__ outB,
               long n8, int ldc8, int gelu)
{
    long i = (long)blockIdx.x * blockDim.x + threadIdx.x;
    long stride = (long)gridDim.x * blockDim.x;
    for (; i < n8; i += stride) {
        long e0 = i * 8;
        float v[8];
        short8 p0 = *(const short8*)(part + e0);
#pragma unroll
        for (int k = 0; k < 8; ++k) v[k] = bf2f((unsigned short)p0[k]);
        for (int s = 1; s < S; ++s) {
            short8 ps = *(const short8*)(part + e0 + (long)s * sPart);
#pragma unroll
            for (int k = 0; k < 8; ++k) v[k] += bf2f((unsigned short)ps[k]);
        }
        if (bias) {
            int c = (int)(i % ldc8) * 8;
            float4 b0 = *(const float4*)(bias + c);
            float4 b1 = *(const float4*)(bias + c + 4);
            v[0] += b0.x; v[1] += b0.y; v[2] += b0.z; v[3] += b0.w;
            v[4] += b1.x; v[5] += b1.y; v[6] += b1.z; v[7] += b1.w;
        }
        if (res) {
            float4 r0 = *(const float4*)(res + e0);
            float4 r1 = *(const float4*)(res + e0 + 4);
            v[0] += r0.x; v[1] += r0.y; v[2] += r0.z; v[3] += r0.w;
            v[4] += r1.x; v[5] += r1.y; v[6] += r1.z; v[7] += r1.w;
        }
        if (gelu) {
#pragma unroll
            for (int k = 0; k < 8; ++k)
                v[k] = 0.5f * v[k] * (1.0f + erff(v[k] * 0.70710678118654752f));
        }
        if (outF) {
            float4 o0 = { v[0], v[1], v[2], v[3] };
            float4 o1 = { v[4], v[5], v[6], v[7] };
            *(float4*)(outF + e0) = o0;
            *(float4*)(outF + e0 + 4) = o1;
        }
        if (outB) {
            short8 o;
#pragma unroll
            for (int k = 0; k < 8; ++k) o[k] = (short)f2bf(v[k]);
            *(short8*)(outB + e0) = o;
        }
    }
}

// ---- fused split-K(bf16) reduce + bias + residual + LayerNorm --------------
__global__ __launch_bounds__(256)
void k_redux_ln_b(const unsigned short* __restrict__ part, long sPart, int S,
                  const float* __restrict__ bias, const float* __restrict__ res,
                  const float* __restrict__ g, const float* __restrict__ bt,
                  float* __restrict__ yf, unsigned short* __restrict__ yb)
{
    int row = blockIdx.x;
    int t = threadIdx.x;
    int lane = t & 63, wid = t >> 6;
    long base = (long)row * 1024 + t * 4;

    ushort4 p0 = *(const ushort4*)(part + base);
    float v0 = bf2f(p0.x), v1 = bf2f(p0.y), v2 = bf2f(p0.z), v3 = bf2f(p0.w);
    for (int s = 1; s < S; ++s) {
        ushort4 ps = *(const ushort4*)(part + base + (long)s * sPart);
        v0 += bf2f(ps.x); v1 += bf2f(ps.y); v2 += bf2f(ps.z); v3 += bf2f(ps.w);
    }
    float4 bv = *(const float4*)(bias + t * 4);
    v0 += bv.x; v1 += bv.y; v2 += bv.z; v3 += bv.w;
    float4 rv = *(const float4*)(res + base);
    v0 += rv.x; v1 += rv.y; v2 += rv.z; v3 += rv.w;

    float s1 = v0 + v1 + v2 + v3;
    float s2 = v0 * v0 + v1 * v1 + v2 * v2 + v3 * v3;
#pragma unroll
    for (int d = 32; d > 0; d >>= 1) { s1 += __shfl_xor(s1, d, 64); s2 += __shfl_xor(s2, d, 64); }
    __shared__ float rs[4], rss[4];
    if (lane == 0) { rs[wid] = s1; rss[wid] = s2; }
    __syncthreads();
    s1 = rs[0] + rs[1] + rs[2] + rs[3];
    s2 = rss[0] + rss[1] + rss[2] + rss[3];
    float mu  = s1 * (1.0f / 1024.0f);
    float var = s2 * (1.0f / 1024.0f) - mu * mu;
    float inv = rsqrtf(var + 1e-5f);

    float4 gv = *(const float4*)(g + t * 4);
    float4 btv = *(const float4*)(bt + t * 4);
    float o0 = (v0 - mu) * inv * gv.x + btv.x;
    float o1 = (v1 - mu) * inv * gv.y + btv.y;
    float o2 = (v2 - mu) * inv * gv.z + btv.z;
    float o3 = (v3 - mu) * inv * gv.w + btv.w;
    float4 of = { o0, o1, o2, o3 };
    ushort4 ob = { f2bf(o0), f2bf(o1), f2bf(o2), f2bf(o3) };
    *(float4*)(yf + base) = of;
    *(ushort4*)(yb + base) = ob;
}

// ---------------------- tiled transpose (bf16) ------------------------------
__global__ __launch_bounds__(256)
void k_tr(const unsigned short* __restrict__ in, unsigned short* __restrict__ out,
          int R, int ldin, int ldout,
          int H, long sIb, long sIh, long sOz)
{
    __shared__ unsigned short tile[32][33];
    int z = blockIdx.z;
    int b = z / H, h = z - b * H;
    const unsigned short* ip = in + (long)b * sIb + (long)h * sIh;
    unsigned short* op = out + (long)z * sOz;
    int t = threadIdx.x;
    int cl = t & 31, rl = t >> 5;
    int c0 = blockIdx.x * 32, r0 = blockIdx.y * 32;
#pragma unroll
    for (int i = 0; i < 4; ++i) {
        int r = r0 + rl + i * 8;
        unsigned short v = 0;
        if (r < R) v = ip[(long)r * ldin + (c0 + cl)];
        tile[rl + i * 8][cl] = v;
    }
    __syncthreads();
#pragma unroll
    for (int i = 0; i < 4; ++i) {
        int orow = c0 + rl + i * 8;
        int ocol = r0 + cl;
        op[(long)orow * ldout + ocol] = tile[cl][rl + i * 8];
    }
}

// --------------------- wave-per-row masked softmax ---------------------------
__global__ __launch_bounds__(256)
void k_softmax_w(const float* __restrict__ sc, long sPart, int S,
                 unsigned short* __restrict__ P,
                 const int* __restrict__ mask, int L, int Lpad,
                 int ld_sc, int ld_p, int rows_per_batch, int nrows)
{
    int gw = (int)((blockIdx.x * 256 + threadIdx.x) >> 6);
    if (gw >= nrows) return;
    int lane = threadIdx.x & 63;
    int b = gw / rows_per_batch;
    const float* p = sc + (long)gw * ld_sc;
    unsigned short* po = P + (long)gw * ld_p;
    const int* mrow = mask + (long)b * L;

    int nch = (Lpad + 255) >> 8;     // 1 or 2
    float v[2][4];
    float mx = -INFINITY;
#pragma unroll
    for (int c = 0; c < 2; ++c) {
        if (c >= nch) { v[c][0]=v[c][1]=v[c][2]=v[c][3] = -INFINITY; continue; }
        int j = c * 256 + lane * 4;
        if (j < L) {
            float4 x = *(const float4*)(p + j);
            for (int s = 1; s < S; ++s) {
                float4 y = *(const float4*)(p + j + (long)s * sPart);
                x.x += y.x; x.y += y.y; x.z += y.z; x.w += y.w;
            }
            int4 m = *(const int4*)(mrow + j);
            v[c][0] = m.x ? x.x : -INFINITY;
            v[c][1] = m.y ? x.y : -INFINITY;
            v[c][2] = m.z ? x.z : -INFINITY;
            v[c][3] = m.w ? x.w : -INFINITY;
        } else {
            v[c][0]=v[c][1]=v[c][2]=v[c][3] = -INFINITY;
        }
        mx = fmaxf(mx, fmaxf(fmaxf(v[c][0], v[c][1]), fmaxf(v[c][2], v[c][3])));
    }
#pragma unroll
    for (int d = 32; d > 0; d >>= 1) mx = fmaxf(mx, __shfl_xor(mx, d, 64));

    float sum = 0.f;
#pragma unroll
    for (int c = 0; c < 2; ++c)
#pragma unroll
        for (int k = 0; k < 4; ++k) {
            float e = (v[c][k] == -INFINITY) ? 0.0f : __expf(v[c][k] - mx);
            v[c][k] = e;
            sum += e;
        }
#pragma unroll
    for (int d = 32; d > 0; d >>= 1) sum += __shfl_xor(sum, d, 64);
    float inv = 1.0f / sum;

#pragma unroll
    for (int c = 0; c < 2; ++c) {
        if (c >= nch) continue;
        int j = c * 256 + lane * 4;
        if (j < Lpad) {
            ushort4 o;
            o.x = f2bf(v[c][0] * inv);
            o.y = f2bf(v[c][1] * inv);
            o.z = f2bf(v[c][2] * inv);
            o.w = f2bf(v[c][3] * inv);
            *(ushort4*)(po + j) = o;
        }
    }
}

// ---------------- combine (bf16 partial aggs) -------------------------------
__global__ void k_combine_b(float* __restrict__ qf, unsigned short* __restrict__ qb,
                            const unsigned short* __restrict__ aggtp,
                            const unsigned short* __restrict__ aggrp,
                            const float* __restrict__ alpha, long n4, long sPart, int S)
{
    float a = *alpha;
    long i = (long)blockIdx.x * blockDim.x + threadIdx.x;
    long stride = (long)gridDim.x * blockDim.x;
    for (; i < n4; i += stride) {
        long e0 = i * 4;
        float st[4] = {0.f, 0.f, 0.f, 0.f}, sr[4] = {0.f, 0.f, 0.f, 0.f};
        for (int s = 0; s < S; ++s) {
            ushort4 pt = *(const ushort4*)(aggtp + e0 + (long)s * sPart);
            ushort4 pr = *(const ushort4*)(aggrp + e0 + (long)s * sPart);
            st[0] += bf2f(pt.x); st[1] += bf2f(pt.y); st[2] += bf2f(pt.z); st[3] += bf2f(pt.w);
            sr[0] += bf2f(pr.x); sr[1] += bf2f(pr.y); sr[2] += bf2f(pr.z); sr[3] += bf2f(pr.w);
        }
        float4 q = *(const float4*)(qf + e0);
        float v0 = q.x + a * sr[0] + (1.0f - a) * st[0];
        float v1 = q.y + a * sr[1] + (1.0f - a) * st[1];
        float v2 = q.z + a * sr[2] + (1.0f - a) * st[2];
        float v3 = q.w + a * sr[3] + (1.0f - a) * st[3];
        float4 of = { v0, v1, v2, v3 };
        ushort4 ob = { f2bf(v0), f2bf(v1), f2bf(v2), f2bf(v3) };
        *(float4*)(qf + e0) = of;
        *(ushort4*)(qb + e0) = ob;
    }
}

// ---------------------------------------------------------------------------
extern "C" void kernel_launch(void* const* d_in, const int* in_sizes, int n_in,
                              void* d_out, int out_size, void* d_ws, size_t ws_size,
                              hipStream_t stream)
{
    const float* queries = (const float*)d_in[0];
    const float* text    = (const float*)d_in[1];
    const float* region  = (const float*)d_in[2];
    const int*   tmask   = (const int*)d_in[3];
    const int*   rmask   = (const int*)d_in[4];
    const float* w_qkv_t = (const float*)d_in[5];
    const float* b_qkv_t = (const float*)d_in[6];
    const float* w_o_t   = (const float*)d_in[7];
    const float* b_o_t   = (const float*)d_in[8];
    const float* w_qkv_r = (const float*)d_in[9];
    const float* b_qkv_r = (const float*)d_in[10];
    const float* w_o_r   = (const float*)d_in[11];
    const float* b_o_r   = (const float*)d_in[12];
    const float* ln_g    = (const float*)d_in[13];
    const float* ln_b    = (const float*)d_in[14];
    const float* w1      = (const float*)d_in[15];
    const float* b1      = (const float*)d_in[16];
    const float* w2      = (const float*)d_in[17];
    const float* b2      = (const float*)d_in[18];
    const float* alpha   = (const float*)d_in[19];

    const int Bn = 16, NQ = 128, LT = 512, LR = 196, D = 1024, H = 16;
    const int LRp = 256;
    const int MQ = Bn * NQ;              // 2048
    const int MT = Bn * LT;              // 8192
    const int MR = Bn * LR;              // 3136

    char* ws = (char*)d_ws;
    size_t off = 0;
    auto alloc = [&](size_t bytes) -> void* {
        void* p = ws + off;
        off = (off + bytes + 255) & ~(size_t)255;
        return p;
    };
    unsigned short* qb     = (unsigned short*)alloc((size_t)MQ * D * 2);
    unsigned short* tb     = (unsigned short*)alloc((size_t)MT * D * 2);
    unsigned short* rb     = (unsigned short*)alloc((size_t)MR * D * 2);
    unsigned short* wqkvtb = (unsigned short*)alloc((size_t)3 * D * D * 2);
    unsigned short* wotb   = (unsigned short*)alloc((size_t)D * D * 2);
    unsigned short* wqkvrb = (unsigned short*)alloc((size_t)3 * D * D * 2);
    unsigned short* worb   = (unsigned short*)alloc((size_t)D * D * 2);
    unsigned short* w1b    = (unsigned short*)alloc((size_t)4 * D * D * 2);
    unsigned short* w2b    = (unsigned short*)alloc((size_t)4 * D * D * 2);
    unsigned short* ktv    = (unsigned short*)alloc((size_t)MT * 2 * D * 2);
    unsigned short* krv    = (unsigned short*)alloc((size_t)MR * 2 * D * 2);
    unsigned short* vtT    = (unsigned short*)alloc((size_t)Bn * H * 64 * LT * 2);
    unsigned short* vrT    = (unsigned short*)alloc((size_t)Bn * H * 64 * LRp * 2);
    unsigned short* qp     = (unsigned short*)alloc((size_t)MQ * D * 2);
    unsigned short* ao     = (unsigned short*)alloc((size_t)MQ * D * 2);
    unsigned short* qlnb   = (unsigned short*)alloc((size_t)MQ * D * 2);
    float* qlf  = (float*)alloc((size_t)MQ * D * 4);
    float* sc   = (float*)alloc((size_t)Bn * H * NQ * LT * 4);   // 67MB arena
    if (off > ws_size) return;

    // phase-reused views
    unsigned short* tbT = ktv;                               // [B][1024][512]
    unsigned short* rbT = ktv + (size_t)Bn * D * LT;         // [B][1024][256p]
    unsigned short* Patt = (unsigned short*)sc;              // MHA P [z][128][Lpad]
    unsigned short* Pt = (unsigned short*)sc;
    unsigned short* Pr = (unsigned short*)(sc + 1 * 1048576);
    float* atp   = sc + 2 * 1048576;
    float* arp   = sc + 6 * 1048576;
    unsigned short* aggtp_b = (unsigned short*)((char*)sc + (size_t)32 * 1048576);
    unsigned short* aggrp_b = (unsigned short*)((char*)sc + (size_t)48 * 1048576);
    unsigned short* hb = (unsigned short*)sc;
    unsigned short* part_qb  = (unsigned short*)sc;
    unsigned short* part_f1b = ktv;

    const long PQ = (long)MQ * D;

    // ---- all converts in one balanced launch ----
    {
        CvtPack pk;
        const float* srcs[9] = { queries, text, region, w_qkv_t, w_o_t, w_qkv_r, w_o_r, w1, w2 };
        unsigned short* dsts[9] = { qb, tb, rb, wqkvtb, wotb, wqkvrb, worb, w1b, w2b };
        long ns[9] = { (long)MQ * D, (long)MT * D, (long)MR * D, (long)3 * D * D,
                       (long)D * D, (long)3 * D * D, (long)D * D, (long)4 * D * D,
                       (long)4 * D * D };
        long acc16 = 0;
        pk.start16[0] = 0;
        for (int i = 0; i < 9; ++i) {
            pk.src[i] = srcs[i]; pk.dst[i] = dsts[i];
            acc16 += ns[i] / 16;
            pk.start16[i + 1] = acc16;
        }
        k_cvt_multi<<<2048, 256, 0, stream>>>(pk, acc16);
    }

    auto NT = [&](const unsigned short* A, const unsigned short* Bm, const float* bias,
                  const float* res, float* oF, unsigned short* oB,
                  int M, int N, int K, int lda, int ldb, int ldc,
                  int Hh, long sAb, long sAh, long sBb, long sBh, long sCb, long sCh,
                  int batch, float scale, bool gelu, int S = 1, long sPart = 0,
                  unsigned short* vT = nullptr, int vColOff = 0, long sVz = 0,
                  int vLd = 0, int rpb = 1) {
        dim3 g((N + 127) / 128, (M + 127) / 128, batch * S);
        if (gelu)
            k_gemm_nt<true><<<g, 256, 0, stream>>>(A, Bm, bias, res, oF, oB, M, N, K,
                lda, ldb, ldc, Hh, sAb, sAh, sBb, sBh, sCb, sCh, scale, S, sPart,
                vT, vColOff, sVz, vLd, rpb);
        else
            k_gemm_nt<false><<<g, 256, 0, stream>>>(A, Bm, bias, res, oF, oB, M, N, K,
                lda, ldb, ldc, Hh, sAb, sAh, sBb, sBh, sCb, sCh, scale, S, sPart,
                vT, vColOff, sVz, vLd, rpb);
    };
    auto NT256 = [&](const unsigned short* A, const unsigned short* Bm, const float* bias,
                     float* oF, unsigned short* oB, int M, int N, int Kc,
                     int lda, int ldb, int ldc, int S, long sPart,
                     unsigned short* vT = nullptr, int vColOff = 0, long sVz = 0,
                     int vLd = 0) {
        dim3 g((N + 255) / 256, (M + 255) / 256, S);
        k_gemm_nt256<<<g, 1024, 0, stream>>>(A, Bm, bias, oF, oB, M, N, Kc,
                                             lda, ldb, ldc, sPart, vT, vColOff, sVz, vLd);
    };
    auto N64 = [&](const unsigned short* A, const unsigned short* Bm, const float* bias,
                   const float* res, float* oF, unsigned short* oB,
                   int M, int N, int K, int lda, int ldb, int ldc,
                   int Hh, long sAb, long sAh, long sBz, long sCb, long sCh, int Z,
                   int gelu = 0, int S = 1, long sPart = 0) {
        dim3 g(N / 64, M / 128, Z * S);
        k_gemm_n64<<<g, 256, 0, stream>>>(A, Bm, bias, res, oF, oB, K,
                                          lda, ldb, ldc, Hh, sAb, sAh, sBz, sCb, sCh,
                                          gelu, S, sPart);
    };
    auto REDUXB = [&](const unsigned short* part, long sPart, int S, const float* bias,
                      const float* res, float* oF, unsigned short* oB,
                      long total, int ldc, int gelu) {
        long n8 = total / 8;
        int blocks = (int)((n8 + 255) / 256);
        if (blocks > 2048) blocks = 2048;
        k_redux_b<<<blocks, 256, 0, stream>>>(part, sPart, S, bias, res, oF, oB,
                                              n8, ldc / 8, gelu);
    };
    auto SMAX = [&](const float* scp, long sPart, int S, unsigned short* P,
                    const int* mask, int L, int Lpad, int ld_sc, int ld_p,
                    int rpb, int nrows) {
        int blocks = (nrows + 3) / 4;
        k_softmax_w<<<blocks, 256, 0, stream>>>(scp, sPart, S, P, mask, L, Lpad,
                                                ld_sc, ld_p, rpb, nrows);
    };

    // ---- fused K+V projections (V written directly transposed) ----
    NT256(tb, wqkvtb + (long)D * D, b_qkv_t + D, nullptr, ktv,
          MT, 2 * D, D, D, D, 2 * D, 1, 0,
          vtT, D, (long)64 * LT, LT);
    NT(rb, wqkvrb + (long)D * D, b_qkv_r + D, nullptr, nullptr, krv,
       MR, 2 * D, D, D, D, 2 * D, 1,0,0,0,0,0,0, 1, 1.0f, false, 1, 0,
       vrT, D, (long)64 * LRp, LRp, LR);

    // ================= MHA 1 (text) =================
    N64(qb, wqkvtb, b_qkv_t, nullptr, nullptr, qp, MQ, D, D, D, D, D,
        1, 0, 0, 0, 0, 0, 1);
    // fused QK^T + mask + softmax -> Patt [z][128][512]
    k_qks<8><<<dim3(1, 1, Bn * H), 1024, 0, stream>>>(
        qp, ktv, Patt, tmask, LT, D, 2 * D, H,
        (long)NQ * D, (long)LT * 2 * D, 0.125f);
    N64(Patt, vtT, nullptr, nullptr, nullptr, ao,
        NQ, 64, LT, LT, LT, D,
        H, (long)H * NQ * LT, (long)NQ * LT, (long)64 * LT,
        (long)NQ * D, 64, Bn * H);
    N64(ao, wotb, nullptr, nullptr, nullptr, part_qb, MQ, D, D, D, D, D,
        1, 0, 0, 0, 0, 0, 1);
    k_redux_ln_b<<<MQ, 256, 0, stream>>>(part_qb, PQ, 1, b_o_t, queries,
                                         ln_g, ln_b, qlf, qlnb);

    // ================= MHA 2 (region) =================
    N64(qlnb, wqkvrb, b_qkv_r, nullptr, nullptr, qp, MQ, D, D, D, D, D,
        1, 0, 0, 0, 0, 0, 1);
    k_qks<4><<<dim3(1, 1, Bn * H), 1024, 0, stream>>>(
        qp, krv, Patt, rmask, LR, D, 2 * D, H,
        (long)NQ * D, (long)LR * 2 * D, 0.125f);
    N64(Patt, vrT, nullptr, nullptr, nullptr, ao,
        NQ, 64, LRp, LRp, LRp, D,
        H, (long)H * NQ * LRp, (long)NQ * LRp, (long)64 * LRp,
        (long)NQ * D, 64, Bn * H);
    N64(ao, worb, nullptr, nullptr, nullptr, part_qb, MQ, D, D, D, D, D,
        1, 0, 0, 0, 0, 0, 1);
    k_redux_ln_b<<<MQ, 256, 0, stream>>>(part_qb, PQ, 1, b_o_r, qlf,
                                         ln_g, ln_b, qlf, qlnb);

    // ================= manual masked cross-attention =================
    {
        dim3 g1(D / 32, LT / 32, Bn);
        k_tr<<<g1, 256, 0, stream>>>(tb, tbT, LT, D, LT, 1, (long)LT * D, 0, (long)D * LT);
        dim3 g2(D / 32, LRp / 32, Bn);
        k_tr<<<g2, 256, 0, stream>>>(rb, rbT, LR, D, LRp, 1, (long)LR * D, 0, (long)D * LRp);
    }
    NT(qlnb, tb, nullptr, nullptr, atp, nullptr, NQ, LT, 256, D, D, LT,
       1, (long)NQ * D, 0, (long)LT * D, 0, (long)NQ * LT, 0, Bn, 0.03125f, false,
       4, (long)Bn * NQ * LT);
    SMAX(atp, (long)Bn * NQ * LT, 4, Pt, tmask, LT, LT, LT, LT, NQ, Bn * NQ);
    NT(Pt, tbT, nullptr, nullptr, nullptr, aggtp_b, NQ, D, 256, LT, LT, D,
       1, (long)NQ * LT, 0, (long)D * LT, 0, (long)NQ * D, 0, Bn, 1.0f, false,
       2, PQ);
    NT(qlnb, rb, nullptr, nullptr, arp, nullptr, NQ, LR, 256, D, D, LRp,
       1, (long)NQ * D, 0, (long)LR * D, 0, (long)NQ * LRp, 0, Bn, 0.03125f, false,
       4, (long)Bn * NQ * LRp);
    SMAX(arp, (long)Bn * NQ * LRp, 4, Pr, rmask, LR, LRp, LRp, LRp, NQ, Bn * NQ);
    NT(Pr, rbT, nullptr, nullptr, nullptr, aggrp_b, NQ, D, 128, LRp, LRp, D,
       1, (long)NQ * LRp, 0, (long)D * LRp, 0, (long)NQ * D, 0, Bn, 1.0f, false,
       2, PQ);

    k_combine_b<<<2048, 256, 0, stream>>>(qlf, qlnb, aggtp_b, aggrp_b, alpha,
                                          (long)MQ * D / 4, PQ, 2);

    // ================= FFN =================
    NT256(qlnb, w1b, nullptr, nullptr, part_f1b, MQ, 4 * D, 512,
          D, D, 4 * D, 2, (long)MQ * 4 * D);
    REDUXB(part_f1b, (long)MQ * 4 * D, 2, b1, nullptr, nullptr, hb,
           (long)MQ * 4 * D, 4 * D, 1);
    N64(hb, w2b, b2, qlf, (float*)d_out, nullptr, MQ, D, 4 * D, 4 * D, 4 * D, D,
        1, 0, 0, 0, 0, 0, 1);
}

// Round 24
// 419.457 us; speedup vs baseline: 1.0399x; 1.0399x over previous
//
#include <hip/hip_runtime.h>
#include <hip/hip_bf16.h>

// ---------------------------------------------------------------------------
// QueryGuidedFusionNet forward on MI355X.
// Round 24: revert N64 to 5-deep (r23's 10-deep was +8us, latency theory
// falsified). FFN2 moves to NT256 split-K=8 (256 blocks, 3MB/XCD L2-resident
// working set vs N64's 10MB thrash) + redux(bias+res)->d_out. Rest = r22.
// ---------------------------------------------------------------------------

typedef __attribute__((ext_vector_type(8))) short short8;   // 8 bf16
typedef __attribute__((ext_vector_type(4))) float f32x4;

#define DEV static __device__ __forceinline__

DEV unsigned short f2bf(float f) {
    unsigned u = __float_as_uint(f);
    u += 0x7fffu + ((u >> 16) & 1u);          // RNE
    return (unsigned short)(u >> 16);
}
DEV float bf2f(unsigned short u) {
    return __uint_as_float(((unsigned)u) << 16);
}

// ------------------------- multi-tensor convert (balanced) ------------------
struct CvtPack {
    const float* src[9];
    unsigned short* dst[9];
    long start16[10];       // prefix sums in 16-element units
};

__global__ __launch_bounds__(256)
void k_cvt_multi(CvtPack p, long total16) {
    long i = (long)blockIdx.x * blockDim.x + threadIdx.x;
    long stride = (long)gridDim.x * blockDim.x;
    for (; i < total16; i += stride) {
        int t = 0;
#pragma unroll
        for (int k = 1; k < 9; ++k) t += (i >= p.start16[k]) ? 1 : 0;
        long off = i - p.start16[t];
        const f32x4* s = (const f32x4*)p.src[t] + off * 4;
        f32x4 a = s[0];
        f32x4 b = s[1];
        f32x4 c = s[2];
        f32x4 d = s[3];
        short8 o0, o1;
        o0[0] = (short)f2bf(a[0]); o0[1] = (short)f2bf(a[1]);
        o0[2] = (short)f2bf(a[2]); o0[3] = (short)f2bf(a[3]);
        o0[4] = (short)f2bf(b[0]); o0[5] = (short)f2bf(b[1]);
        o0[6] = (short)f2bf(b[2]); o0[7] = (short)f2bf(b[3]);
        o1[0] = (short)f2bf(c[0]); o1[1] = (short)f2bf(c[1]);
        o1[2] = (short)f2bf(c[2]); o1[3] = (short)f2bf(c[3]);
        o1[4] = (short)f2bf(d[0]); o1[5] = (short)f2bf(d[1]);
        o1[6] = (short)f2bf(d[2]); o1[7] = (short)f2bf(d[3]);
        short8* dp = (short8*)p.dst[t] + off * 2;
        dp[0] = o0;
        dp[1] = o1;
    }
}

// ---- fused QK^T + mask + softmax -> compact bf16 P --------------------------
// One block per (b,h): 16 waves compute the full 128 x Lpad score tile.
// NJ = cols-per-wave/16 (8 for Lpad=512, 4 for Lpad=256). K = 64 exact.
template<int NJ>
__global__ __launch_bounds__(1024)
void k_qks(const unsigned short* __restrict__ Q, const unsigned short* __restrict__ Km,
           unsigned short* __restrict__ P, const int* __restrict__ mask,
           int L, int lda, int ldb, int H, long sQb, long sKb, float scale)
{
    const int Lpad = NJ * 64;
    __shared__ unsigned short sm[8192 + 32768];   // Q 16KB + K <=64KB
    __shared__ float redm[128][4];
    __shared__ float reds[128][4];

    int z = blockIdx.z;
    int b = z / H, h = z - b * H;
    const unsigned short* Qp = Q + (long)b * sQb + (long)h * 64;
    const unsigned short* Kp = Km + (long)b * sKb + (long)h * 64;
    unsigned short* Pp = P + (long)z * 128 * Lpad;
    const int* mrow = mask + (long)b * L;

    int t = threadIdx.x;
    int wid = t >> 6, lane = t & 63;
    int lrow = lane & 15, kgrp = lane >> 4;
    int wm = (wid >> 2) * 32;                 // m-wave: 4 x 32 rows
    int wn = (wid & 3) * (NJ * 16);           // n-wave: 4 x NJ*16 cols

    // ---- stage Q (16KB, 1 round) + K (NJ/2 rounds of 16KB) ----
    {
        int d = t * 16;
        int row = d >> 7;
        int colb = (d & 127) ^ ((row & 7) << 4);
        __builtin_amdgcn_global_load_lds(
            (const __attribute__((address_space(1))) unsigned int*)(Qp + (long)row * lda + (colb >> 1)),
            (__attribute__((address_space(3))) unsigned int*)(sm + (d >> 1)), 16, 0, 0);
    }
#pragma unroll
    for (int r = 0; r < NJ / 2; ++r) {
        int full = r * 16384 + t * 16;
        int row = full >> 7;
        int colb = (full & 127) ^ ((row & 7) << 4);
        int kr = row; if (kr > L - 1) kr = L - 1;
        __builtin_amdgcn_global_load_lds(
            (const __attribute__((address_space(1))) unsigned int*)(Kp + (long)kr * ldb + (colb >> 1)),
            (__attribute__((address_space(3))) unsigned int*)(sm + 8192 + (full >> 1)), 16, 0, 0);
    }
    asm volatile("s_waitcnt vmcnt(0)" ::: "memory");
    __builtin_amdgcn_sched_barrier(0);
    __syncthreads();

    // ---- QK^T: acc[2][NJ], K=64 (2 k-chunks) ----
    const char* Qs = (const char*)sm;
    const char* Ks = (const char*)(sm + 8192);
    f32x4 acc[2][NJ] = {};
#pragma unroll
    for (int ks = 0; ks < 2; ++ks) {
        int kb = ks * 64 + kgrp * 16;
        short8 a[2], bb[NJ];
#pragma unroll
        for (int i = 0; i < 2; ++i) {
            int row = wm + i * 16 + lrow;
            a[i] = *(const short8*)(Qs + row * 128 + (kb ^ ((row & 7) << 4)));
        }
#pragma unroll
        for (int j = 0; j < NJ; ++j) {
            int row = wn + j * 16 + lrow;
            bb[j] = *(const short8*)(Ks + row * 128 + (kb ^ ((row & 7) << 4)));
        }
#pragma unroll
        for (int i = 0; i < 2; ++i)
#pragma unroll
            for (int j = 0; j < NJ; ++j)
                acc[i][j] = __builtin_amdgcn_mfma_f32_16x16x32_bf16(a[i], bb[j], acc[i][j], 0, 0, 0);
    }

    // ---- column validity (same for all rows of this thread) ----
    bool okj[NJ];
#pragma unroll
    for (int j = 0; j < NJ; ++j) {
        int c = wn + j * 16 + lrow;
        okj[j] = (c < L) && (mrow[c] != 0);
    }

    // ---- pass 1: row max (16-lane shfl reduce + cross-wave LDS) ----
    int nw = wid & 3;
#pragma unroll
    for (int i = 0; i < 2; ++i) {
#pragma unroll
        for (int e = 0; e < 4; ++e) {
            float m = -INFINITY;
#pragma unroll
            for (int j = 0; j < NJ; ++j)
                if (okj[j]) m = fmaxf(m, acc[i][j][e] * scale);
#pragma unroll
            for (int d = 1; d < 16; d <<= 1) m = fmaxf(m, __shfl_xor(m, d, 64));
            int rl = wm + i * 16 + kgrp * 4 + e;
            if (lrow == 0) redm[rl][nw] = m;
        }
    }
    __syncthreads();

    // ---- pass 2: exp + row sum ----
#pragma unroll
    for (int i = 0; i < 2; ++i) {
#pragma unroll
        for (int e = 0; e < 4; ++e) {
            int rl = wm + i * 16 + kgrp * 4 + e;
            float m = fmaxf(fmaxf(redm[rl][0], redm[rl][1]),
                            fmaxf(redm[rl][2], redm[rl][3]));
            float s = 0.f;
#pragma unroll
            for (int j = 0; j < NJ; ++j) {
                float ev = okj[j] ? __expf(acc[i][j][e] * scale - m) : 0.0f;
                acc[i][j][e] = ev;
                s += ev;
            }
#pragma unroll
            for (int d = 1; d < 16; d <<= 1) s += __shfl_xor(s, d, 64);
            if (lrow == 0) reds[rl][nw] = s;
        }
    }
    __syncthreads();

    // ---- normalize + write compact bf16 P ----
#pragma unroll
    for (int i = 0; i < 2; ++i) {
#pragma unroll
        for (int e = 0; e < 4; ++e) {
            int rl = wm + i * 16 + kgrp * 4 + e;
            float inv = 1.0f / (reds[rl][0] + reds[rl][1] + reds[rl][2] + reds[rl][3]);
            unsigned short* pr = Pp + (long)rl * Lpad;
#pragma unroll
            for (int j = 0; j < NJ; ++j) {
                int c = wn + j * 16 + lrow;
                pr[c] = f2bf(acc[i][j][e] * inv);
            }
        }
    }
}

// --------------------- GEMM NT 256x256 (16 waves, BK=64) --------------------
__global__ __launch_bounds__(1024)
void k_gemm_nt256(const unsigned short* __restrict__ A, const unsigned short* __restrict__ B,
                  const float* __restrict__ bias,
                  float* __restrict__ outF, unsigned short* __restrict__ outB,
                  int M, int N, int K, int lda, int ldb, int ldc,
                  long sPart,
                  unsigned short* __restrict__ vT, int vColOff, long sVz, int vLd)
{
    __shared__ unsigned short smem[2 * 32768];   // 2 bufs x (A32KB + B32KB)

    unsigned gx = gridDim.x, gy = gridDim.y;
    unsigned nwg = gx * gy * gridDim.z;
    unsigned lin = (blockIdx.z * gy + blockIdx.y) * gx + blockIdx.x;
    unsigned bx = blockIdx.x, by = blockIdx.y, bz = blockIdx.z;
    if ((nwg & 7u) == 0u) {
        unsigned cpx = nwg >> 3;
        unsigned s = (lin & 7u) * cpx + (lin >> 3);
        bx = s % gx; unsigned r2 = s / gx;
        by = r2 % gy; bz = r2 / gy;
    }
    int s_k = (int)bz;
    const unsigned short* Ap = A + (long)s_k * K;
    const unsigned short* Bp = B + (long)s_k * K;
    float* outFp = outF ? outF + (long)s_k * sPart : nullptr;
    unsigned short* outBp = outB ? outB + (long)s_k * sPart : nullptr;

    int t = threadIdx.x;
    int wid = t >> 6, lane = t & 63;
    int lrow = lane & 15, kgrp = lane >> 4;
    int tm = by * 256, tn = bx * 256;
    int wm = (wid >> 2) * 64, wn = (wid & 3) * 64;

    auto stage = [&](int buf, int k0) {
#pragma unroll
        for (int r = 0; r < 2; ++r) {
            int d = r * 16384 + t * 16;                 // byte in 32KB tile
            int row = d >> 7;                           // 128B rows
            int colb = (d & 127) ^ ((row & 7) << 4);    // inverse swizzle
            int gr = tm + row; if (gr > M - 1) gr = M - 1;
            const unsigned short* srcA = Ap + (long)gr * lda + k0 + (colb >> 1);
            unsigned short* dstA = smem + ((buf * 65536 + d) >> 1);
            __builtin_amdgcn_global_load_lds(
                (const __attribute__((address_space(1))) unsigned int*)srcA,
                (__attribute__((address_space(3))) unsigned int*)dstA, 16, 0, 0);
            int gn = tn + row; if (gn > N - 1) gn = N - 1;
            const unsigned short* srcB = Bp + (long)gn * ldb + k0 + (colb >> 1);
            unsigned short* dstB = smem + ((buf * 65536 + 32768 + d) >> 1);
            __builtin_amdgcn_global_load_lds(
                (const __attribute__((address_space(1))) unsigned int*)srcB,
                (__attribute__((address_space(3))) unsigned int*)dstB, 16, 0, 0);
        }
    };

    f32x4 acc[4][4] = {};
    int nt = K >> 6;

    stage(0, 0);

    for (int ti = 0; ti < nt; ++ti) {
        int cur = ti & 1;
        if (ti + 1 < nt) {
            stage(cur ^ 1, (ti + 1) << 6);   // 4 new VMEM instrs in flight
            asm volatile("s_waitcnt vmcnt(4)" ::: "memory");   // current tile done
        } else {
            asm volatile("s_waitcnt vmcnt(0)" ::: "memory");
        }
        __builtin_amdgcn_sched_barrier(0);
        __builtin_amdgcn_s_barrier();
        __builtin_amdgcn_sched_barrier(0);

        const char* Ab = (const char*)smem + cur * 65536;
        const char* Bb = Ab + 32768;
#pragma unroll
        for (int ks = 0; ks < 2; ++ks) {
            short8 a[4], bb[4];
            int kb = ks * 64 + kgrp * 16;
#pragma unroll
            for (int i = 0; i < 4; ++i) {
                int row = wm + i * 16 + lrow;
                a[i] = *(const short8*)(Ab + row * 128 + (kb ^ ((row & 7) << 4)));
            }
#pragma unroll
            for (int j = 0; j < 4; ++j) {
                int row = wn + j * 16 + lrow;
                bb[j] = *(const short8*)(Bb + row * 128 + (kb ^ ((row & 7) << 4)));
            }
#pragma unroll
            for (int i = 0; i < 4; ++i)
#pragma unroll
                for (int j = 0; j < 4; ++j)
                    acc[i][j] = __builtin_amdgcn_mfma_f32_16x16x32_bf16(a[i], bb[j], acc[i][j], 0, 0, 0);
        }
        __builtin_amdgcn_s_barrier();   // protect buf before re-stage next iter
    }

#pragma unroll
    for (int i = 0; i < 4; ++i) {
        int rbase = tm + wm + i * 16 + kgrp * 4;
#pragma unroll
        for (int j = 0; j < 4; ++j) {
            int c = tn + wn + j * 16 + lrow;
            if (c >= N) continue;
            float bv = bias ? bias[c] : 0.0f;
            float v[4];
#pragma unroll
            for (int e = 0; e < 4; ++e) v[e] = acc[i][j][e] + bv;
            if (vT && c >= vColOff) {
                if (rbase + 3 < M) {
                    int hh = (c - vColOff) >> 6, dd = (c - vColOff) & 63;
                    int bb2 = rbase >> 9, l = rbase & 511;
                    ushort4 o = { f2bf(v[0]), f2bf(v[1]), f2bf(v[2]), f2bf(v[3]) };
                    *(ushort4*)(vT + (long)(bb2 * 16 + hh) * sVz + (long)dd * vLd + l) = o;
                }
            } else {
#pragma unroll
                for (int e = 0; e < 4; ++e) {
                    int r = rbase + e;
                    if (r >= M) continue;
                    long oidx = (long)r * ldc + c;
                    if (outFp) outFp[oidx] = v[e];
                    if (outBp) outBp[oidx] = f2bf(v[e]);
                }
            }
        }
    }
}

// --------------------- GEMM N64: 128x64 tile (4 waves, 5-deep) --------------
__global__ __launch_bounds__(256)
void k_gemm_n64(const unsigned short* __restrict__ A, const unsigned short* __restrict__ B,
                const float* __restrict__ bias, const float* __restrict__ res,
                float* __restrict__ outF, unsigned short* __restrict__ outB,
                int K, int lda, int ldb, int ldc,
                int H, long sAb, long sAh, long sBz, long sCb, long sCh, int gelu,
                int S, long sPart)
{
    __shared__ unsigned short smem[5 * 6144];   // 5 x (A 8KB + B 4KB)

    unsigned gx = gridDim.x, gy = gridDim.y;
    unsigned nwg = gx * gy * gridDim.z;
    unsigned lin = (blockIdx.z * gy + blockIdx.y) * gx + blockIdx.x;
    unsigned bx = blockIdx.x, by = blockIdx.y, bz = blockIdx.z;
    if ((nwg & 7u) == 0u) {
        unsigned cpx = nwg >> 3;
        unsigned s = (lin & 7u) * cpx + (lin >> 3);
        bx = s % gx; unsigned r2 = s / gx;
        by = r2 % gy; bz = r2 / gy;
    }

    int zz = (int)bz;
    int s_k = 0;
    if (S > 1) { s_k = zz % S; zz /= S; }
    int b = zz / H, h = zz - b * H;
    const unsigned short* Ap = A + (long)b * sAb + (long)h * sAh + (long)s_k * K;
    const unsigned short* Bp = B + (long)zz * sBz + (long)s_k * K;
    float* outFp = outF;
    unsigned short* outBp = outB;
    if (outBp && S > 1) outBp += (long)s_k * sPart;
    long offC = (long)b * sCb + (long)h * sCh;

    int t = threadIdx.x;
    int wid = t >> 6, lane = t & 63;
    int lrow = lane & 15, kgrp = lane >> 4;
    int tm = by * 128, tn = bx * 64;
    int wm = wid * 32;

    auto stage = [&](int buf, int k0) {
#pragma unroll
        for (int r = 0; r < 2; ++r) {               // A: 128 rows x 64B
            int d = r * 4096 + t * 16;
            int row = d >> 6;
            int colb = (d & 63) ^ (((row >> 1) & 3) << 4);
            const unsigned short* srcA = Ap + (long)(tm + row) * lda + k0 + (colb >> 1);
            unsigned short* dstA = smem + ((buf * 12288 + d) >> 1);
            __builtin_amdgcn_global_load_lds(
                (const __attribute__((address_space(1))) unsigned int*)srcA,
                (__attribute__((address_space(3))) unsigned int*)dstA, 16, 0, 0);
        }
        {                                            // B: 64 rows x 64B
            int d = t * 16;
            int row = d >> 6;
            int colb = (d & 63) ^ (((row >> 1) & 3) << 4);
            const unsigned short* srcB = Bp + (long)(tn + row) * ldb + k0 + (colb >> 1);
            unsigned short* dstB = smem + ((buf * 12288 + 8192 + d) >> 1);
            __builtin_amdgcn_global_load_lds(
                (const __attribute__((address_space(1))) unsigned int*)srcB,
                (__attribute__((address_space(3))) unsigned int*)dstB, 16, 0, 0);
        }
    };

    f32x4 acc[2][4] = {};
    int nt = K >> 5;

    for (int p = 0; p < 4 && p < nt; ++p) stage(p, p << 5);

    for (int ti = 0; ti < nt; ++ti) {
        int cur = ti % 5;
        int rem = nt - 1 - ti;
        if (rem >= 3)      asm volatile("s_waitcnt vmcnt(9)" ::: "memory");
        else if (rem == 2) asm volatile("s_waitcnt vmcnt(6)" ::: "memory");
        else if (rem == 1) asm volatile("s_waitcnt vmcnt(3)" ::: "memory");
        else               asm volatile("s_waitcnt vmcnt(0)" ::: "memory");
        __builtin_amdgcn_sched_barrier(0);
        __builtin_amdgcn_s_barrier();
        __builtin_amdgcn_sched_barrier(0);

        if (ti + 4 < nt) stage((ti + 4) % 5, (ti + 4) << 5);

        const char* Ab = (const char*)smem + cur * 12288;
        const char* Bb = Ab + 8192;
        short8 a[2], bb[4];
#pragma unroll
        for (int i = 0; i < 2; ++i) {
            int row = wm + i * 16 + lrow;
            a[i] = *(const short8*)(Ab + row * 64 + ((kgrp * 16) ^ (((row >> 1) & 3) << 4)));
        }
#pragma unroll
        for (int j = 0; j < 4; ++j) {
            int row = j * 16 + lrow;
            bb[j] = *(const short8*)(Bb + row * 64 + ((kgrp * 16) ^ (((row >> 1) & 3) << 4)));
        }
#pragma unroll
        for (int i = 0; i < 2; ++i)
#pragma unroll
            for (int j = 0; j < 4; ++j)
                acc[i][j] = __builtin_amdgcn_mfma_f32_16x16x32_bf16(a[i], bb[j], acc[i][j], 0, 0, 0);
    }

#pragma unroll
    for (int i = 0; i < 2; ++i) {
        int rbase = tm + wm + i * 16 + kgrp * 4;
#pragma unroll
        for (int j = 0; j < 4; ++j) {
            int c = tn + j * 16 + lrow;
            float bv = bias ? bias[c] : 0.0f;
#pragma unroll
            for (int e = 0; e < 4; ++e) {
                int r = rbase + e;
                long oidx = offC + (long)r * ldc + c;
                float v = acc[i][j][e] + bv;
                if (res) v += res[oidx];
                if (gelu) v = 0.5f * v * (1.0f + erff(v * 0.70710678118654752f));
                if (outFp) outFp[oidx] = v;
                if (outBp) outBp[oidx] = f2bf(v);
            }
        }
    }
}

// ------------------------------ GEMM NT (pipelined 128²) --------------------
template<bool GELU>
__global__ __launch_bounds__(256)
void k_gemm_nt(const unsigned short* __restrict__ A, const unsigned short* __restrict__ B,
               const float* __restrict__ bias, const float* __restrict__ res,
               float* __restrict__ outF, unsigned short* __restrict__ outB,
               int M, int N, int K, int lda, int ldb, int ldc,
               int H, long sAb, long sAh, long sBb, long sBh, long sCb, long sCh,
               float scale, int S, long sPart,
               unsigned short* __restrict__ vT, int vColOff, long sVz, int vLd, int rpb)
{
    __shared__ unsigned short smem[5 * 8192];

    unsigned gx = gridDim.x, gy = gridDim.y, gz = gridDim.z;
    unsigned nwg = gx * gy * gz;
    unsigned lin = (blockIdx.z * gy + blockIdx.y) * gx + blockIdx.x;
    unsigned bx = blockIdx.x, by = blockIdx.y, bz = blockIdx.z;
    if ((nwg & 7u) == 0u) {
        unsigned cpx = nwg >> 3;
        unsigned s = (lin & 7u) * cpx + (lin >> 3);
        bx = s % gx; unsigned r2 = s / gx;
        by = r2 % gy; bz = r2 / gy;
    }

    int zz = (int)bz;
    int s_k = 0;
    if (S > 1) { s_k = zz % S; zz /= S; }
    int b = zz / H, h = zz - b * H;
    const unsigned short* Ap = A + (long)b * sAb + (long)h * sAh + (long)s_k * K;
    const unsigned short* Bp = B + (long)b * sBb + (long)h * sBh + (long)s_k * K;
    float* outFp = outF;
    if (outFp && S > 1) outFp += (long)s_k * sPart;
    unsigned short* outBp = outB;
    if (outBp && S > 1) outBp += (long)s_k * sPart;
    long offC = (long)b * sCb + (long)h * sCh;

    int t    = threadIdx.x;
    int wid  = t >> 6;
    int lane = t & 63;
    int lrow = lane & 15;
    int kgrp = lane >> 4;

    int tm = by * 128;
    int tn = bx * 128;
    int wm = (wid >> 1) * 64;
    int wn = (wid & 1) * 64;

    auto stage = [&](int buf, int k0) {
#pragma unroll
        for (int r = 0; r < 2; ++r) {
            int d = r * 4096 + t * 16;
            int row = d >> 6;
            int colb = (d & 63) ^ (((row >> 1) & 3) << 4);
            int gr = tm + row; if (gr > M - 1) gr = M - 1;
            const unsigned short* srcA = Ap + (long)gr * lda + k0 + (colb >> 1);
            unsigned short* dstA = smem + ((buf * 16384 + r * 4096 + wid * 1024) >> 1);
            __builtin_amdgcn_global_load_lds(
                (const __attribute__((address_space(1))) unsigned int*)srcA,
                (__attribute__((address_space(3))) unsigned int*)dstA, 16, 0, 0);
            int gn = tn + row; if (gn > N - 1) gn = N - 1;
            const unsigned short* srcB = Bp + (long)gn * ldb + k0 + (colb >> 1);
            unsigned short* dstB = smem + ((buf * 16384 + 8192 + r * 4096 + wid * 1024) >> 1);
            __builtin_amdgcn_global_load_lds(
                (const __attribute__((address_space(1))) unsigned int*)srcB,
                (__attribute__((address_space(3))) unsigned int*)dstB, 16, 0, 0);
        }
    };

    f32x4 acc[4][4] = {};
    int nt = K >> 5;

    for (int p = 0; p < 4 && p < nt; ++p) stage(p, p << 5);

    for (int ti = 0; ti < nt; ++ti) {
        int cur = ti % 5;
        int rem = nt - 1 - ti;
        if (rem >= 3)      asm volatile("s_waitcnt vmcnt(12)" ::: "memory");
        else if (rem == 2) asm volatile("s_waitcnt vmcnt(8)"  ::: "memory");
        else if (rem == 1) asm volatile("s_waitcnt vmcnt(4)"  ::: "memory");
        else               asm volatile("s_waitcnt vmcnt(0)"  ::: "memory");
        __builtin_amdgcn_sched_barrier(0);
        __builtin_amdgcn_s_barrier();
        __builtin_amdgcn_sched_barrier(0);

        if (ti + 4 < nt) stage((ti + 4) % 5, (ti + 4) << 5);

        const char* Ab = (const char*)smem + cur * 16384;
        const char* Bb = Ab + 8192;
        short8 a[4], bb[4];
#pragma unroll
        for (int i = 0; i < 4; ++i) {
            int row = wm + i * 16 + lrow;
            a[i] = *(const short8*)(Ab + row * 64 + ((kgrp * 16) ^ (((row >> 1) & 3) << 4)));
        }
#pragma unroll
        for (int j = 0; j < 4; ++j) {
            int row = wn + j * 16 + lrow;
            bb[j] = *(const short8*)(Bb + row * 64 + ((kgrp * 16) ^ (((row >> 1) & 3) << 4)));
        }
#pragma unroll
        for (int i = 0; i < 4; ++i)
#pragma unroll
            for (int j = 0; j < 4; ++j)
                acc[i][j] = __builtin_amdgcn_mfma_f32_16x16x32_bf16(a[i], bb[j], acc[i][j], 0, 0, 0);
    }

#pragma unroll
    for (int i = 0; i < 4; ++i) {
        int rbase = tm + wm + i * 16 + kgrp * 4;
#pragma unroll
        for (int j = 0; j < 4; ++j) {
            int c = tn + wn + j * 16 + lrow;
            if (c >= N) continue;
            float bv = bias ? bias[c] : 0.0f;
            if (vT && c >= vColOff) {
                int hh = (c - vColOff) >> 6, dd = (c - vColOff) & 63;
#pragma unroll
                for (int e = 0; e < 4; ++e) {
                    int r = rbase + e;
                    if (r >= M) continue;
                    float v = acc[i][j][e] * scale + bv;
                    int bb2 = r / rpb, l = r - bb2 * rpb;
                    vT[(long)(bb2 * 16 + hh) * sVz + (long)dd * vLd + l] = f2bf(v);
                }
                continue;
            }
#pragma unroll
            for (int e = 0; e < 4; ++e) {
                int r = rbase + e;
                if (r >= M) continue;
                float v = acc[i][j][e] * scale + bv;
                long oidx = offC + (long)r * ldc + c;
                if (res) v += res[oidx];
                if (GELU) v = 0.5f * v * (1.0f + erff(v * 0.70710678118654752f));
                if (outFp) outFp[oidx] = v;
                if (outBp) outBp[oidx] = f2bf(v);
            }
        }
    }
}

// -------------------- split-K reduce (bf16 partials) -------------------------
__global__ __launch_bounds__(256)
void k_redux_b(const unsigned short* __restrict__ part, long sPart, int S,
               const float* __restrict__ bias, const float* __restrict__ res,
               float* __restrict__ outF, unsigned short* __restrict__ outB,
               long n8, int ldc8, int gelu)
{
    long i = (long)blockIdx.x * blockDim.x + threadIdx.x;
    long stride = (long)gridDim.x * blockDim.x;
    for (; i < n8; i += stride) {
        long e0 = i * 8;
        float v[8];
        short8 p0 = *(const short8*)(part + e0);
#pragma unroll
        for (int k = 0; k < 8; ++k) v[k] = bf2f((unsigned short)p0[k]);
        for (int s = 1; s < S; ++s) {
            short8 ps = *(const short8*)(part + e0 + (long)s * sPart);
#pragma unroll
            for (int k = 0; k < 8; ++k) v[k] += bf2f((unsigned short)ps[k]);
        }
        if (bias) {
            int c = (int)(i % ldc8) * 8;
            float4 b0 = *(const float4*)(bias + c);
            float4 b1 = *(const float4*)(bias + c + 4);
            v[0] += b0.x; v[1] += b0.y; v[2] += b0.z; v[3] += b0.w;
            v[4] += b1.x; v[5] += b1.y; v[6] += b1.z; v[7] += b1.w;
        }
        if (res) {
            float4 r0 = *(const float4*)(res + e0);
            float4 r1 = *(const float4*)(res + e0 + 4);
            v[0] += r0.x; v[1] += r0.y; v[2] += r0.z; v[3] += r0.w;
            v[4] += r1.x; v[5] += r1.y; v[6] += r1.z; v[7] += r1.w;
        }
        if (gelu) {
#pragma unroll
            for (int k = 0; k < 8; ++k)
                v[k] = 0.5f * v[k] * (1.0f + erff(v[k] * 0.70710678118654752f));
        }
        if (outF) {
            float4 o0 = { v[0], v[1], v[2], v[3] };
            float4 o1 = { v[4], v[5], v[6], v[7] };
            *(float4*)(outF + e0) = o0;
            *(float4*)(outF + e0 + 4) = o1;
        }
        if (outB) {
            short8 o;
#pragma unroll
            for (int k = 0; k < 8; ++k) o[k] = (short)f2bf(v[k]);
            *(short8*)(outB + e0) = o;
        }
    }
}

// ---- fused split-K(bf16) reduce + bias + residual + LayerNorm --------------
__global__ __launch_bounds__(256)
void k_redux_ln_b(const unsigned short* __restrict__ part, long sPart, int S,
                  const float* __restrict__ bias, const float* __restrict__ res,
                  const float* __restrict__ g, const float* __restrict__ bt,
                  float* __restrict__ yf, unsigned short* __restrict__ yb)
{
    int row = blockIdx.x;
    int t = threadIdx.x;
    int lane = t & 63, wid = t >> 6;
    long base = (long)row * 1024 + t * 4;

    ushort4 p0 = *(const ushort4*)(part + base);
    float v0 = bf2f(p0.x), v1 = bf2f(p0.y), v2 = bf2f(p0.z), v3 = bf2f(p0.w);
    for (int s = 1; s < S; ++s) {
        ushort4 ps = *(const ushort4*)(part + base + (long)s * sPart);
        v0 += bf2f(ps.x); v1 += bf2f(ps.y); v2 += bf2f(ps.z); v3 += bf2f(ps.w);
    }
    float4 bv = *(const float4*)(bias + t * 4);
    v0 += bv.x; v1 += bv.y; v2 += bv.z; v3 += bv.w;
    float4 rv = *(const float4*)(res + base);
    v0 += rv.x; v1 += rv.y; v2 += rv.z; v3 += rv.w;

    float s1 = v0 + v1 + v2 + v3;
    float s2 = v0 * v0 + v1 * v1 + v2 * v2 + v3 * v3;
#pragma unroll
    for (int d = 32; d > 0; d >>= 1) { s1 += __shfl_xor(s1, d, 64); s2 += __shfl_xor(s2, d, 64); }
    __shared__ float rs[4], rss[4];
    if (lane == 0) { rs[wid] = s1; rss[wid] = s2; }
    __syncthreads();
    s1 = rs[0] + rs[1] + rs[2] + rs[3];
    s2 = rss[0] + rss[1] + rss[2] + rss[3];
    float mu  = s1 * (1.0f / 1024.0f);
    float var = s2 * (1.0f / 1024.0f) - mu * mu;
    float inv = rsqrtf(var + 1e-5f);

    float4 gv = *(const float4*)(g + t * 4);
    float4 btv = *(const float4*)(bt + t * 4);
    float o0 = (v0 - mu) * inv * gv.x + btv.x;
    float o1 = (v1 - mu) * inv * gv.y + btv.y;
    float o2 = (v2 - mu) * inv * gv.z + btv.z;
    float o3 = (v3 - mu) * inv * gv.w + btv.w;
    float4 of = { o0, o1, o2, o3 };
    ushort4 ob = { f2bf(o0), f2bf(o1), f2bf(o2), f2bf(o3) };
    *(float4*)(yf + base) = of;
    *(ushort4*)(yb + base) = ob;
}

// ---------------------- tiled transpose (bf16) ------------------------------
__global__ __launch_bounds__(256)
void k_tr(const unsigned short* __restrict__ in, unsigned short* __restrict__ out,
          int R, int ldin, int ldout,
          int H, long sIb, long sIh, long sOz)
{
    __shared__ unsigned short tile[32][33];
    int z = blockIdx.z;
    int b = z / H, h = z - b * H;
    const unsigned short* ip = in + (long)b * sIb + (long)h * sIh;
    unsigned short* op = out + (long)z * sOz;
    int t = threadIdx.x;
    int cl = t & 31, rl = t >> 5;
    int c0 = blockIdx.x * 32, r0 = blockIdx.y * 32;
#pragma unroll
    for (int i = 0; i < 4; ++i) {
        int r = r0 + rl + i * 8;
        unsigned short v = 0;
        if (r < R) v = ip[(long)r * ldin + (c0 + cl)];
        tile[rl + i * 8][cl] = v;
    }
    __syncthreads();
#pragma unroll
    for (int i = 0; i < 4; ++i) {
        int orow = c0 + rl + i * 8;
        int ocol = r0 + cl;
        op[(long)orow * ldout + ocol] = tile[cl][rl + i * 8];
    }
}

// --------------------- wave-per-row masked softmax ---------------------------
__global__ __launch_bounds__(256)
void k_softmax_w(const float* __restrict__ sc, long sPart, int S,
                 unsigned short* __restrict__ P,
                 const int* __restrict__ mask, int L, int Lpad,
                 int ld_sc, int ld_p, int rows_per_batch, int nrows)
{
    int gw = (int)((blockIdx.x * 256 + threadIdx.x) >> 6);
    if (gw >= nrows) return;
    int lane = threadIdx.x & 63;
    int b = gw / rows_per_batch;
    const float* p = sc + (long)gw * ld_sc;
    unsigned short* po = P + (long)gw * ld_p;
    const int* mrow = mask + (long)b * L;

    int nch = (Lpad + 255) >> 8;     // 1 or 2
    float v[2][4];
    float mx = -INFINITY;
#pragma unroll
    for (int c = 0; c < 2; ++c) {
        if (c >= nch) { v[c][0]=v[c][1]=v[c][2]=v[c][3] = -INFINITY; continue; }
        int j = c * 256 + lane * 4;
        if (j < L) {
            float4 x = *(const float4*)(p + j);
            for (int s = 1; s < S; ++s) {
                float4 y = *(const float4*)(p + j + (long)s * sPart);
                x.x += y.x; x.y += y.y; x.z += y.z; x.w += y.w;
            }
            int4 m = *(const int4*)(mrow + j);
            v[c][0] = m.x ? x.x : -INFINITY;
            v[c][1] = m.y ? x.y : -INFINITY;
            v[c][2] = m.z ? x.z : -INFINITY;
            v[c][3] = m.w ? x.w : -INFINITY;
        } else {
            v[c][0]=v[c][1]=v[c][2]=v[c][3] = -INFINITY;
        }
        mx = fmaxf(mx, fmaxf(fmaxf(v[c][0], v[c][1]), fmaxf(v[c][2], v[c][3])));
    }
#pragma unroll
    for (int d = 32; d > 0; d >>= 1) mx = fmaxf(mx, __shfl_xor(mx, d, 64));

    float sum = 0.f;
#pragma unroll
    for (int c = 0; c < 2; ++c)
#pragma unroll
        for (int k = 0; k < 4; ++k) {
            float e = (v[c][k] == -INFINITY) ? 0.0f : __expf(v[c][k] - mx);
            v[c][k] = e;
            sum += e;
        }
#pragma unroll
    for (int d = 32; d > 0; d >>= 1) sum += __shfl_xor(sum, d, 64);
    float inv = 1.0f / sum;

#pragma unroll
    for (int c = 0; c < 2; ++c) {
        if (c >= nch) continue;
        int j = c * 256 + lane * 4;
        if (j < Lpad) {
            ushort4 o;
            o.x = f2bf(v[c][0] * inv);
            o.y = f2bf(v[c][1] * inv);
            o.z = f2bf(v[c][2] * inv);
            o.w = f2bf(v[c][3] * inv);
            *(ushort4*)(po + j) = o;
        }
    }
}

// ---------------- combine (bf16 partial aggs) -------------------------------
__global__ void k_combine_b(float* __restrict__ qf, unsigned short* __restrict__ qb,
                            const unsigned short* __restrict__ aggtp,
                            const unsigned short* __restrict__ aggrp,
                            const float* __restrict__ alpha, long n4, long sPart, int S)
{
    float a = *alpha;
    long i = (long)blockIdx.x * blockDim.x + threadIdx.x;
    long stride = (long)gridDim.x * blockDim.x;
    for (; i < n4; i += stride) {
        long e0 = i * 4;
        float st[4] = {0.f, 0.f, 0.f, 0.f}, sr[4] = {0.f, 0.f, 0.f, 0.f};
        for (int s = 0; s < S; ++s) {
            ushort4 pt = *(const ushort4*)(aggtp + e0 + (long)s * sPart);
            ushort4 pr = *(const ushort4*)(aggrp + e0 + (long)s * sPart);
            st[0] += bf2f(pt.x); st[1] += bf2f(pt.y); st[2] += bf2f(pt.z); st[3] += bf2f(pt.w);
            sr[0] += bf2f(pr.x); sr[1] += bf2f(pr.y); sr[2] += bf2f(pr.z); sr[3] += bf2f(pr.w);
        }
        float4 q = *(const float4*)(qf + e0);
        float v0 = q.x + a * sr[0] + (1.0f - a) * st[0];
        float v1 = q.y + a * sr[1] + (1.0f - a) * st[1];
        float v2 = q.z + a * sr[2] + (1.0f - a) * st[2];
        float v3 = q.w + a * sr[3] + (1.0f - a) * st[3];
        float4 of = { v0, v1, v2, v3 };
        ushort4 ob = { f2bf(v0), f2bf(v1), f2bf(v2), f2bf(v3) };
        *(float4*)(qf + e0) = of;
        *(ushort4*)(qb + e0) = ob;
    }
}

// ---------------------------------------------------------------------------
extern "C" void kernel_launch(void* const* d_in, const int* in_sizes, int n_in,
                              void* d_out, int out_size, void* d_ws, size_t ws_size,
                              hipStream_t stream)
{
    const float* queries = (const float*)d_in[0];
    const float* text    = (const float*)d_in[1];
    const float* region  = (const float*)d_in[2];
    const int*   tmask   = (const int*)d_in[3];
    const int*   rmask   = (const int*)d_in[4];
    const float* w_qkv_t = (const float*)d_in[5];
    const float* b_qkv_t = (const float*)d_in[6];
    const float* w_o_t   = (const float*)d_in[7];
    const float* b_o_t   = (const float*)d_in[8];
    const float* w_qkv_r = (const float*)d_in[9];
    const float* b_qkv_r = (const float*)d_in[10];
    const float* w_o_r   = (const float*)d_in[11];
    const float* b_o_r   = (const float*)d_in[12];
    const float* ln_g    = (const float*)d_in[13];
    const float* ln_b    = (const float*)d_in[14];
    const float* w1      = (const float*)d_in[15];
    const float* b1      = (const float*)d_in[16];
    const float* w2      = (const float*)d_in[17];
    const float* b2      = (const float*)d_in[18];
    const float* alpha   = (const float*)d_in[19];

    const int Bn = 16, NQ = 128, LT = 512, LR = 196, D = 1024, H = 16;
    const int LRp = 256;
    const int MQ = Bn * NQ;              // 2048
    const int MT = Bn * LT;              // 8192
    const int MR = Bn * LR;              // 3136

    char* ws = (char*)d_ws;
    size_t off = 0;
    auto alloc = [&](size_t bytes) -> void* {
        void* p = ws + off;
        off = (off + bytes + 255) & ~(size_t)255;
        return p;
    };
    unsigned short* qb     = (unsigned short*)alloc((size_t)MQ * D * 2);
    unsigned short* tb     = (unsigned short*)alloc((size_t)MT * D * 2);
    unsigned short* rb     = (unsigned short*)alloc((size_t)MR * D * 2);
    unsigned short* wqkvtb = (unsigned short*)alloc((size_t)3 * D * D * 2);
    unsigned short* wotb   = (unsigned short*)alloc((size_t)D * D * 2);
    unsigned short* wqkvrb = (unsigned short*)alloc((size_t)3 * D * D * 2);
    unsigned short* worb   = (unsigned short*)alloc((size_t)D * D * 2);
    unsigned short* w1b    = (unsigned short*)alloc((size_t)4 * D * D * 2);
    unsigned short* w2b    = (unsigned short*)alloc((size_t)4 * D * D * 2);
    unsigned short* ktv    = (unsigned short*)alloc((size_t)MT * 2 * D * 2);
    unsigned short* krv    = (unsigned short*)alloc((size_t)MR * 2 * D * 2);
    unsigned short* vtT    = (unsigned short*)alloc((size_t)Bn * H * 64 * LT * 2);
    unsigned short* vrT    = (unsigned short*)alloc((size_t)Bn * H * 64 * LRp * 2);
    unsigned short* qp     = (unsigned short*)alloc((size_t)MQ * D * 2);
    unsigned short* ao     = (unsigned short*)alloc((size_t)MQ * D * 2);
    unsigned short* qlnb   = (unsigned short*)alloc((size_t)MQ * D * 2);
    float* qlf  = (float*)alloc((size_t)MQ * D * 4);
    float* sc   = (float*)alloc((size_t)Bn * H * NQ * LT * 4);   // 67MB arena
    if (off > ws_size) return;

    // phase-reused views
    unsigned short* tbT = ktv;                               // [B][1024][512]
    unsigned short* rbT = ktv + (size_t)Bn * D * LT;         // [B][1024][256p]
    unsigned short* Patt = (unsigned short*)sc;              // MHA P [z][128][Lpad]
    unsigned short* Pt = (unsigned short*)sc;
    unsigned short* Pr = (unsigned short*)(sc + 1 * 1048576);
    float* atp   = sc + 2 * 1048576;
    float* arp   = sc + 6 * 1048576;
    unsigned short* aggtp_b = (unsigned short*)((char*)sc + (size_t)32 * 1048576);
    unsigned short* aggrp_b = (unsigned short*)((char*)sc + (size_t)48 * 1048576);
    unsigned short* hb = (unsigned short*)sc;
    unsigned short* part_qb  = (unsigned short*)sc;
    unsigned short* part_f1b = ktv;
    unsigned short* part_f2b = ktv;          // reused after FFN1 redux drains it

    const long PQ = (long)MQ * D;

    // ---- all converts in one balanced launch ----
    {
        CvtPack pk;
        const float* srcs[9] = { queries, text, region, w_qkv_t, w_o_t, w_qkv_r, w_o_r, w1, w2 };
        unsigned short* dsts[9] = { qb, tb, rb, wqkvtb, wotb, wqkvrb, worb, w1b, w2b };
        long ns[9] = { (long)MQ * D, (long)MT * D, (long)MR * D, (long)3 * D * D,
                       (long)D * D, (long)3 * D * D, (long)D * D, (long)4 * D * D,
                       (long)4 * D * D };
        long acc16 = 0;
        pk.start16[0] = 0;
        for (int i = 0; i < 9; ++i) {
            pk.src[i] = srcs[i]; pk.dst[i] = dsts[i];
            acc16 += ns[i] / 16;
            pk.start16[i + 1] = acc16;
        }
        k_cvt_multi<<<2048, 256, 0, stream>>>(pk, acc16);
    }

    auto NT = [&](const unsigned short* A, const unsigned short* Bm, const float* bias,
                  const float* res, float* oF, unsigned short* oB,
                  int M, int N, int K, int lda, int ldb, int ldc,
                  int Hh, long sAb, long sAh, long sBb, long sBh, long sCb, long sCh,
                  int batch, float scale, bool gelu, int S = 1, long sPart = 0,
                  unsigned short* vT = nullptr, int vColOff = 0, long sVz = 0,
                  int vLd = 0, int rpb = 1) {
        dim3 g((N + 127) / 128, (M + 127) / 128, batch * S);
        if (gelu)
            k_gemm_nt<true><<<g, 256, 0, stream>>>(A, Bm, bias, res, oF, oB, M, N, K,
                lda, ldb, ldc, Hh, sAb, sAh, sBb, sBh, sCb, sCh, scale, S, sPart,
                vT, vColOff, sVz, vLd, rpb);
        else
            k_gemm_nt<false><<<g, 256, 0, stream>>>(A, Bm, bias, res, oF, oB, M, N, K,
                lda, ldb, ldc, Hh, sAb, sAh, sBb, sBh, sCb, sCh, scale, S, sPart,
                vT, vColOff, sVz, vLd, rpb);
    };
    auto NT256 = [&](const unsigned short* A, const unsigned short* Bm, const float* bias,
                     float* oF, unsigned short* oB, int M, int N, int Kc,
                     int lda, int ldb, int ldc, int S, long sPart,
                     unsigned short* vT = nullptr, int vColOff = 0, long sVz = 0,
                     int vLd = 0) {
        dim3 g((N + 255) / 256, (M + 255) / 256, S);
        k_gemm_nt256<<<g, 1024, 0, stream>>>(A, Bm, bias, oF, oB, M, N, Kc,
                                             lda, ldb, ldc, sPart, vT, vColOff, sVz, vLd);
    };
    auto N64 = [&](const unsigned short* A, const unsigned short* Bm, const float* bias,
                   const float* res, float* oF, unsigned short* oB,
                   int M, int N, int K, int lda, int ldb, int ldc,
                   int Hh, long sAb, long sAh, long sBz, long sCb, long sCh, int Z,
                   int gelu = 0, int S = 1, long sPart = 0) {
        dim3 g(N / 64, M / 128, Z * S);
        k_gemm_n64<<<g, 256, 0, stream>>>(A, Bm, bias, res, oF, oB, K,
                                          lda, ldb, ldc, Hh, sAb, sAh, sBz, sCb, sCh,
                                          gelu, S, sPart);
    };
    auto REDUXB = [&](const unsigned short* part, long sPart, int S, const float* bias,
                      const float* res, float* oF, unsigned short* oB,
                      long total, int ldc, int gelu) {
        long n8 = total / 8;
        int blocks = (int)((n8 + 255) / 256);
        if (blocks > 2048) blocks = 2048;
        k_redux_b<<<blocks, 256, 0, stream>>>(part, sPart, S, bias, res, oF, oB,
                                              n8, ldc / 8, gelu);
    };
    auto SMAX = [&](const float* scp, long sPart, int S, unsigned short* P,
                    const int* mask, int L, int Lpad, int ld_sc, int ld_p,
                    int rpb, int nrows) {
        int blocks = (nrows + 3) / 4;
        k_softmax_w<<<blocks, 256, 0, stream>>>(scp, sPart, S, P, mask, L, Lpad,
                                                ld_sc, ld_p, rpb, nrows);
    };

    // ---- fused K+V projections (V written directly transposed) ----
    NT256(tb, wqkvtb + (long)D * D, b_qkv_t + D, nullptr, ktv,
          MT, 2 * D, D, D, D, 2 * D, 1, 0,
          vtT, D, (long)64 * LT, LT);
    NT(rb, wqkvrb + (long)D * D, b_qkv_r + D, nullptr, nullptr, krv,
       MR, 2 * D, D, D, D, 2 * D, 1,0,0,0,0,0,0, 1, 1.0f, false, 1, 0,
       vrT, D, (long)64 * LRp, LRp, LR);

    // ================= MHA 1 (text) =================
    N64(qb, wqkvtb, b_qkv_t, nullptr, nullptr, qp, MQ, D, D, D, D, D,
        1, 0, 0, 0, 0, 0, 1);
    // fused QK^T + mask + softmax -> Patt [z][128][512]
    k_qks<8><<<dim3(1, 1, Bn * H), 1024, 0, stream>>>(
        qp, ktv, Patt, tmask, LT, D, 2 * D, H,
        (long)NQ * D, (long)LT * 2 * D, 0.125f);
    N64(Patt, vtT, nullptr, nullptr, nullptr, ao,
        NQ, 64, LT, LT, LT, D,
        H, (long)H * NQ * LT, (long)NQ * LT, (long)64 * LT,
        (long)NQ * D, 64, Bn * H);
    N64(ao, wotb, nullptr, nullptr, nullptr, part_qb, MQ, D, D, D, D, D,
        1, 0, 0, 0, 0, 0, 1);
    k_redux_ln_b<<<MQ, 256, 0, stream>>>(part_qb, PQ, 1, b_o_t, queries,
                                         ln_g, ln_b, qlf, qlnb);

    // ================= MHA 2 (region) =================
    N64(qlnb, wqkvrb, b_qkv_r, nullptr, nullptr, qp, MQ, D, D, D, D, D,
        1, 0, 0, 0, 0, 0, 1);
    k_qks<4><<<dim3(1, 1, Bn * H), 1024, 0, stream>>>(
        qp, krv, Patt, rmask, LR, D, 2 * D, H,
        (long)NQ * D, (long)LR * 2 * D, 0.125f);
    N64(Patt, vrT, nullptr, nullptr, nullptr, ao,
        NQ, 64, LRp, LRp, LRp, D,
        H, (long)H * NQ * LRp, (long)NQ * LRp, (long)64 * LRp,
        (long)NQ * D, 64, Bn * H);
    N64(ao, worb, nullptr, nullptr, nullptr, part_qb, MQ, D, D, D, D, D,
        1, 0, 0, 0, 0, 0, 1);
    k_redux_ln_b<<<MQ, 256, 0, stream>>>(part_qb, PQ, 1, b_o_r, qlf,
                                         ln_g, ln_b, qlf, qlnb);

    // ================= manual masked cross-attention =================
    {
        dim3 g1(D / 32, LT / 32, Bn);
        k_tr<<<g1, 256, 0, stream>>>(tb, tbT, LT, D, LT, 1, (long)LT * D, 0, (long)D * LT);
        dim3 g2(D / 32, LRp / 32, Bn);
        k_tr<<<g2, 256, 0, stream>>>(rb, rbT, LR, D, LRp, 1, (long)LR * D, 0, (long)D * LRp);
    }
    NT(qlnb, tb, nullptr, nullptr, atp, nullptr, NQ, LT, 256, D, D, LT,
       1, (long)NQ * D, 0, (long)LT * D, 0, (long)NQ * LT, 0, Bn, 0.03125f, false,
       4, (long)Bn * NQ * LT);
    SMAX(atp, (long)Bn * NQ * LT, 4, Pt, tmask, LT, LT, LT, LT, NQ, Bn * NQ);
    NT(Pt, tbT, nullptr, nullptr, nullptr, aggtp_b, NQ, D, 256, LT, LT, D,
       1, (long)NQ * LT, 0, (long)D * LT, 0, (long)NQ * D, 0, Bn, 1.0f, false,
       2, PQ);
    NT(qlnb, rb, nullptr, nullptr, arp, nullptr, NQ, LR, 256, D, D, LRp,
       1, (long)NQ * D, 0, (long)LR * D, 0, (long)NQ * LRp, 0, Bn, 0.03125f, false,
       4, (long)Bn * NQ * LRp);
    SMAX(arp, (long)Bn * NQ * LRp, 4, Pr, rmask, LR, LRp, LRp, LRp, NQ, Bn * NQ);
    NT(Pr, rbT, nullptr, nullptr, nullptr, aggrp_b, NQ, D, 128, LRp, LRp, D,
       1, (long)NQ * LRp, 0, (long)D * LRp, 0, (long)NQ * D, 0, Bn, 1.0f, false,
       2, PQ);

    k_combine_b<<<2048, 256, 0, stream>>>(qlf, qlnb, aggtp_b, aggrp_b, alpha,
                                          (long)MQ * D / 4, PQ, 2);

    // ================= FFN =================
    // FFN1: NT256 S=2 + redux (partials in ktv, drained into hb=sc)
    NT256(qlnb, w1b, nullptr, nullptr, part_f1b, MQ, 4 * D, 512,
          D, D, 4 * D, 2, (long)MQ * 4 * D);
    REDUXB(part_f1b, (long)MQ * 4 * D, 2, b1, nullptr, nullptr, hb,
           (long)MQ * 4 * D, 4 * D, 1);
    // FFN2: NT256 split-K=8 (256 blocks, L2-resident 3MB/XCD chunks)
    // -> 8 bf16 partial slices in ktv -> redux(bias+res) -> fp32 d_out
    NT256(hb, w2b, nullptr, nullptr, part_f2b, MQ, D, 512,
          4 * D, 4 * D, D, 8, PQ);
    REDUXB(part_f2b, PQ, 8, b2, qlf, (float*)d_out, nullptr, PQ, D, 0);
}